// Round 1
// baseline (790.625 us; speedup 1.0000x reference)
//
#include <hip/hip_runtime.h>
#include <math.h>

#define BB 4
#define NN 8192
#define IND 1024
#define HID 512
#define HEADS 8
#define KSEL 16
#define NCLS 2
#define HH 91
#define NPIX 8281   // 91*91
#define NTOK 8282   // +cls
#define MROWS 32768 // B*N

typedef short short8 __attribute__((ext_vector_type(8)));
typedef float floatx4 __attribute__((ext_vector_type(4)));

__device__ __forceinline__ unsigned short f2bf(float f) {
  union { float f; unsigned u; } v; v.f = f;
  unsigned r = (v.u + 0x7FFFu + ((v.u >> 16) & 1u)) >> 16;
  return (unsigned short)r;
}
__device__ __forceinline__ float bf2f(unsigned short h) {
  union { unsigned u; float f; } v; v.u = ((unsigned)h) << 16;
  return v.f;
}

__device__ __forceinline__ void gld16(const unsigned short* g, void* l) {
  typedef __attribute__((address_space(1))) const void GV;
  typedef __attribute__((address_space(3))) void LV;
  __builtin_amdgcn_global_load_lds((GV*)g, (LV*)l, 16, 0, 0);
}

// ---------------- u = W_feat @ w_enc (fp32, exact scores path) ----------------
__global__ void k_u(const float* __restrict__ W, const float* __restrict__ we,
                    float* __restrict__ u) {
  int wave = threadIdx.x >> 6, lane = threadIdx.x & 63;
  int k = blockIdx.x * 4 + wave;
  const float* wr = W + (long)k * HID + lane * 8;
  const float* wer = we + lane * 8;
  float a = 0.f;
#pragma unroll
  for (int i = 0; i < 8; ++i) a = fmaf(wr[i], wer[i], a);
  for (int off = 32; off; off >>= 1) a += __shfl_down(a, off);
  if (lane == 0) u[k] = a;
}

// ---------------- W_feat -> bf16 transposed [n][k] ----------------
__global__ void k_wt(const float* __restrict__ W, unsigned short* __restrict__ Wt) {
  __shared__ unsigned short s[64][68];
  int kt = blockIdx.x * 64, nt = blockIdx.y * 64;
  int tid = threadIdx.x;
#pragma unroll
  for (int i = 0; i < 16; ++i) {
    int idx = tid + i * 256;
    int kk2 = idx >> 6, nn2 = idx & 63;
    s[nn2][kk2] = f2bf(W[(long)(kt + kk2) * HID + nt + nn2]);
  }
  __syncthreads();
#pragma unroll
  for (int i = 0; i < 16; ++i) {
    int idx = tid + i * 256;
    int nn2 = idx >> 6, kk2 = idx & 63;
    Wt[(long)(nt + nn2) * IND + kt + kk2] = s[nn2][kk2];
  }
}

// ------------- inputs fp32 -> bf16 copy + exact fp32 score logits -------------
__global__ void k_cvt(const float* __restrict__ in, const float* __restrict__ u,
                      unsigned short* __restrict__ abf, float* __restrict__ slog) {
  __shared__ float su[IND];
  int tid = threadIdx.x;
  for (int i = tid; i < IND; i += 256) su[i] = u[i];
  __syncthreads();
  int wave = tid >> 6, lane = tid & 63;
  long row = (long)blockIdx.x * 4 + wave;
  const float* ip = in + row * IND;
  unsigned short* op = abf + row * IND;
  float acc = 0.f;
#pragma unroll
  for (int p = 0; p < 4; ++p) {
    int k = p * 256 + lane * 4;
    float4 v = *(const float4*)(ip + k);
    ushort4 o;
    o.x = f2bf(v.x); o.y = f2bf(v.y); o.z = f2bf(v.z); o.w = f2bf(v.w);
    *(ushort4*)(op + k) = o;
    acc += v.x * su[k] + v.y * su[k + 1] + v.z * su[k + 2] + v.w * su[k + 3];
  }
  for (int off = 32; off; off >>= 1) acc += __shfl_down(acc, off);
  if (lane == 0) slog[row] = acc;
}

// ---------------- GEMM1: x = inputs @ W_feat + b_feat (bf16 MFMA) ----------------
__global__ void k_gemm(const unsigned short* __restrict__ A,
                       const unsigned short* __restrict__ Bt,
                       const float* __restrict__ bias,
                       unsigned short* __restrict__ X) {
  __shared__ unsigned short sA[128 * 32];
  __shared__ unsigned short sB[128 * 32];
  int tid = threadIdx.x;
  int wave = tid >> 6, lane = tid & 63;
  long m0 = (long)blockIdx.x * 128;
  int n0 = blockIdx.y * 128;
  int wm = (wave >> 1) * 64, wn = (wave & 1) * 64;
  int lm = lane & 15, lk = (lane >> 4) * 8;
  floatx4 acc[4][4];
#pragma unroll
  for (int i = 0; i < 4; ++i)
#pragma unroll
    for (int j = 0; j < 4; ++j) acc[i][j] = (floatx4){0.f, 0.f, 0.f, 0.f};

  const unsigned short* gA = A + (m0 + (tid >> 2)) * IND + (tid & 3) * 8;
  const unsigned short* gB = Bt + (long)(n0 + (tid >> 2)) * IND + (tid & 3) * 8;
  char* sAc = (char*)sA + wave * 1024;
  char* sBc = (char*)sB + wave * 1024;

  for (int k0 = 0; k0 < IND; k0 += 32) {
    gld16(gA + k0, sAc);
    gld16(gA + k0 + 64 * IND, sAc + 4096);
    gld16(gB + k0, sBc);
    gld16(gB + k0 + 64 * IND, sBc + 4096);
    __syncthreads();
    short8 af[4], bfr[4];
#pragma unroll
    for (int i = 0; i < 4; ++i)
      af[i] = *(const short8*)(sA + (wm + i * 16 + lm) * 32 + lk);
#pragma unroll
    for (int j = 0; j < 4; ++j)
      bfr[j] = *(const short8*)(sB + (wn + j * 16 + lm) * 32 + lk);
#pragma unroll
    for (int i = 0; i < 4; ++i)
#pragma unroll
      for (int j = 0; j < 4; ++j)
        acc[i][j] = __builtin_amdgcn_mfma_f32_16x16x32_bf16(af[i], bfr[j], acc[i][j], 0, 0, 0);
    __syncthreads();
  }
#pragma unroll
  for (int j = 0; j < 4; ++j) {
    int gcol = n0 + wn + j * 16 + lm;
    float bv_ = bias[gcol];
#pragma unroll
    for (int i = 0; i < 4; ++i) {
      long grow = m0 + wm + i * 16 + (lane >> 4) * 4;
#pragma unroll
      for (int r = 0; r < 4; ++r)
        X[(grow + r) * HID + gcol] = f2bf(acc[i][j][r] + bv_);
    }
  }
}

// ---------------- top-K (exact fp32 scores) + Q = mean of selected rows ----------------
__global__ void k_topq(const float* __restrict__ slog, const unsigned short* __restrict__ X,
                       float* __restrict__ Q) {
  __shared__ float sc[NN];
  __shared__ float rv[256];
  __shared__ int ri[256];
  __shared__ int wi[KSEL];
  int b = blockIdx.x, tid = threadIdx.x;
  for (int i = tid; i < NN; i += 256) sc[i] = slog[b * NN + i];
  __syncthreads();
  for (int it = 0; it < KSEL; ++it) {
    float bv = -3.4e38f; int bi = 0x7FFFFFFF;
    for (int i = tid; i < NN; i += 256) {
      float v = sc[i];
      if (v > bv) { bv = v; bi = i; }
    }
    rv[tid] = bv; ri[tid] = bi;
    __syncthreads();
    for (int s = 128; s; s >>= 1) {
      if (tid < s) {
        float v2 = rv[tid + s]; int i2 = ri[tid + s];
        if (v2 > rv[tid] || (v2 == rv[tid] && i2 < ri[tid])) { rv[tid] = v2; ri[tid] = i2; }
      }
      __syncthreads();
    }
    if (tid == 0) { wi[it] = ri[0]; sc[ri[0]] = -3.4e38f; }
    __syncthreads();
  }
  for (int c = tid; c < HID; c += 256) {
    float s = 0.f;
    for (int t2 = 0; t2 < KSEL; ++t2)
      s += bf2f(X[((long)b * NN + wi[t2]) * HID + c]);
    Q[b * HID + c] = s * (1.f / KSEL);
  }
}

// ------- x2 = relu(x - Q); depthwise 3x3 conv (SAME) + conv_b + residual -> x̃ rows 1.. -------
__global__ void k_conv(const unsigned short* __restrict__ X, const float* __restrict__ Q,
                       const float* __restrict__ cw, const float* __restrict__ cb,
                       unsigned short* __restrict__ XT) {
  int tid = threadIdx.x;
  int b = blockIdx.y;
  int c = tid * 2;
  float w0[9], w1[9];
#pragma unroll
  for (int t = 0; t < 9; ++t) { w0[t] = cw[c * 9 + t]; w1[t] = cw[(c + 1) * 9 + t]; }
  float q0 = Q[b * HID + c], q1 = Q[b * HID + c + 1];
  float cb0 = cb[c], cb1 = cb[c + 1];
  int nbase = blockIdx.x * 64;
  const unsigned short* xb = X + (long)b * NN * HID;
  for (int ii = 0; ii < 64; ++ii) {
    int n = nbase + ii;
    if (n >= NPIX) break;
    int h = n / HH, w = n - h * HH;
    float a0 = 0.f, a1 = 0.f, c0v = 0.f, c1v = 0.f;
#pragma unroll
    for (int dy = 0; dy < 3; ++dy) {
      int hh2 = h + dy - 1;
      if (hh2 < 0 || hh2 >= HH) continue;
#pragma unroll
      for (int dx = 0; dx < 3; ++dx) {
        int ww2 = w + dx - 1;
        if (ww2 < 0 || ww2 >= HH) continue;
        int n2 = hh2 * HH + ww2;
        int r = n2 < NN ? n2 : n2 - NN;
        unsigned v = *(const unsigned*)(xb + (long)r * HID + c);
        float f0 = bf2f((unsigned short)(v & 0xFFFF));
        float f1 = bf2f((unsigned short)(v >> 16));
        f0 = fmaxf(f0 - q0, 0.f);
        f1 = fmaxf(f1 - q1, 0.f);
        int t = dy * 3 + dx;
        a0 = fmaf(w0[t], f0, a0);
        a1 = fmaf(w1[t], f1, a1);
        if (t == 4) { c0v = f0; c1v = f1; }
      }
    }
    unsigned out = (unsigned)f2bf(a0 + cb0 + c0v) | ((unsigned)f2bf(a1 + cb1 + c1v) << 16);
    *(unsigned*)(XT + ((long)b * NTOK + 1 + n) * HID + c) = out;
  }
}

// ------- qvec = Q@Wq+bq; t[h] = Wk[:,h]·q_h; bkq[h]; write cls row of x̃ -------
__global__ void k_qprep(const float* __restrict__ Q, const float* __restrict__ Wq,
                        const float* __restrict__ bq, const float* __restrict__ Wk,
                        const float* __restrict__ bk, const float* __restrict__ cls,
                        float* __restrict__ qvec, float* __restrict__ tmat,
                        float* __restrict__ bkq, unsigned short* __restrict__ XT) {
  __shared__ float sq[HID];
  __shared__ float qv[HID];
  int b = blockIdx.x, tid = threadIdx.x;
  for (int i = tid; i < HID; i += 256) sq[i] = Q[b * HID + i];
  __syncthreads();
  for (int c = tid; c < HID; c += 256) {
    float a = bq[c];
    for (int j = 0; j < HID; ++j) a = fmaf(sq[j], Wq[j * HID + c], a);
    qv[c] = a;
    qvec[b * HID + c] = a;
  }
  __syncthreads();
  for (int idx = tid; idx < HEADS * HID; idx += 256) {
    int h = idx >> 9, c = idx & 511;
    float a = 0.f;
    const float* wr = Wk + (long)c * HID + h * 64;
    const float* qh = qv + h * 64;
#pragma unroll 8
    for (int d = 0; d < 64; ++d) a = fmaf(wr[d], qh[d], a);
    tmat[((long)b * HEADS + h) * HID + c] = a;
  }
  if (tid < HEADS) {
    float a = 0.f;
    for (int d = 0; d < 64; ++d) a = fmaf(bk[tid * 64 + d], qv[tid * 64 + d], a);
    bkq[b * HEADS + tid] = a;
  }
  for (int c = tid; c < HID; c += 256)
    XT[(long)b * NTOK * HID + c] = f2bf(cls[c]);
}

// ---------------- logits[b,h,n] = (x̃[n]·t[h] + bkq[h]) / sqrt(512) ----------------
__global__ void k_logits(const unsigned short* __restrict__ XT, const float* __restrict__ tmat,
                         const float* __restrict__ bkq, float* __restrict__ logits) {
  __shared__ float st[HEADS * HID];
  __shared__ float sb[HEADS];
  int b = blockIdx.y, tid = threadIdx.x;
  for (int i = tid; i < HEADS * HID; i += 256) st[i] = tmat[(long)b * HEADS * HID + i];
  if (tid < HEADS) sb[tid] = bkq[b * HEADS + tid];
  __syncthreads();
  int wave = tid >> 6, lane = tid & 63;
  float tr[HEADS][8];
#pragma unroll
  for (int h = 0; h < HEADS; ++h)
#pragma unroll
    for (int i = 0; i < 8; ++i) tr[h][i] = st[h * HID + lane * 8 + i];
  float sbr[HEADS];
#pragma unroll
  for (int h = 0; h < HEADS; ++h) sbr[h] = sb[h];

  for (long row = blockIdx.x * 4 + wave; row < NTOK; row += 4L * gridDim.x) {
    const unsigned short* xr = XT + ((long)b * NTOK + row) * HID + lane * 8;
    ushort4 v0 = *(const ushort4*)xr;
    ushort4 v1 = *(const ushort4*)(xr + 4);
    float xf[8] = {bf2f(v0.x), bf2f(v0.y), bf2f(v0.z), bf2f(v0.w),
                   bf2f(v1.x), bf2f(v1.y), bf2f(v1.z), bf2f(v1.w)};
    float acc[HEADS];
#pragma unroll
    for (int h = 0; h < HEADS; ++h) {
      float a = 0.f;
#pragma unroll
      for (int i = 0; i < 8; ++i) a = fmaf(xf[i], tr[h][i], a);
      acc[h] = a;
    }
#pragma unroll
    for (int h = 0; h < HEADS; ++h)
      for (int off = 32; off; off >>= 1) acc[h] += __shfl_down(acc[h], off);
    if (lane == 0) {
#pragma unroll
      for (int h = 0; h < HEADS; ++h)
        logits[((long)b * HEADS + h) * NTOK + row] = (acc[h] + sbr[h]) * 0.044194173824159216f;
    }
  }
}

// ---------------- softmax in place over n ----------------
__global__ void k_soft(float* __restrict__ logits) {
  __shared__ float red[256];
  int b = blockIdx.x, tid = threadIdx.x;
  for (int h = 0; h < HEADS; ++h) {
    float* lp = logits + ((long)b * HEADS + h) * NTOK;
    float m = -3.4e38f;
    for (int i = tid; i < NTOK; i += 256) m = fmaxf(m, lp[i]);
    red[tid] = m; __syncthreads();
    for (int s = 128; s; s >>= 1) { if (tid < s) red[tid] = fmaxf(red[tid], red[tid + s]); __syncthreads(); }
    m = red[0]; __syncthreads();
    float sm = 0.f;
    for (int i = tid; i < NTOK; i += 256) sm += __expf(lp[i] - m);
    red[tid] = sm; __syncthreads();
    for (int s = 128; s; s >>= 1) { if (tid < s) red[tid] += red[tid + s]; __syncthreads(); }
    float inv = 1.f / red[0]; __syncthreads();
    for (int i = tid; i < NTOK; i += 256) lp[i] = __expf(lp[i] - m) * inv;
    __syncthreads();
  }
}

// ---------------- wsum[b,h,:] = sum_n P[h,n] * x̃[n,:] ----------------
__global__ void k_wsum(const unsigned short* __restrict__ XT, const float* __restrict__ P,
                       float* __restrict__ wsum) {
  __shared__ float pw[HEADS * 128];
  int b = blockIdx.y, tid = threadIdx.x;
  int nbase = blockIdx.x * 128;
  for (int i = tid; i < HEADS * 128; i += 256) {
    int h = i >> 7, nn = i & 127;
    long n = nbase + nn;
    pw[i] = (n < NTOK) ? P[((long)b * HEADS + h) * NTOK + n] : 0.f;
  }
  __syncthreads();
  int c = tid * 2;
  float wa[HEADS][2];
#pragma unroll
  for (int h = 0; h < HEADS; ++h) { wa[h][0] = 0.f; wa[h][1] = 0.f; }
  int lim = NTOK - nbase; if (lim > 128) lim = 128;
  for (int nn = 0; nn < lim; ++nn) {
    unsigned v = *(const unsigned*)(XT + ((long)b * NTOK + nbase + nn) * HID + c);
    float f0 = bf2f((unsigned short)(v & 0xFFFF));
    float f1 = bf2f((unsigned short)(v >> 16));
#pragma unroll
    for (int h = 0; h < HEADS; ++h) {
      float p = pw[h * 128 + nn];
      wa[h][0] = fmaf(p, f0, wa[h][0]);
      wa[h][1] = fmaf(p, f1, wa[h][1]);
    }
  }
#pragma unroll
  for (int h = 0; h < HEADS; ++h) {
    atomicAdd(&wsum[((long)b * HEADS + h) * HID + c], wa[h][0]);
    atomicAdd(&wsum[((long)b * HEADS + h) * HID + c + 1], wa[h][1]);
  }
}

// ---------------- O = qvec + wsum@Wv + bv ----------------
__global__ void k_o1(const float* __restrict__ qvec, const float* __restrict__ wsum,
                     const float* __restrict__ Wv, const float* __restrict__ bv,
                     float* __restrict__ O) {
  int b = blockIdx.x >> 2, cs = (blockIdx.x & 3) * 128;
  int c = cs + threadIdx.x;
  int h = c >> 6;
  const float* wp = wsum + ((long)b * HEADS + h) * HID;
  float a = bv[c];
  for (int j = 0; j < HID; ++j) a = fmaf(wp[j], Wv[(long)j * HID + c], a);
  O[b * HID + c] = qvec[b * HID + c] + a;
}

// ---------------- O2 = O + relu(O@Wo+bo);  out = O2@Wc + bc ----------------
__global__ void k_o2(const float* __restrict__ O, const float* __restrict__ Wo,
                     const float* __restrict__ bo, const float* __restrict__ Wc,
                     const float* __restrict__ bc, float* __restrict__ out) {
  __shared__ float so[HID];
  __shared__ float r0[128], r1[128];
  int b = blockIdx.x >> 2, cs = (blockIdx.x & 3) * 128;
  int tid = threadIdx.x;
  for (int i = tid; i < HID; i += 128) so[i] = O[b * HID + i];
  __syncthreads();
  int c = cs + tid;
  float a = bo[c];
  for (int j = 0; j < HID; ++j) a = fmaf(so[j], Wo[(long)j * HID + c], a);
  float o2 = so[c] + fmaxf(a, 0.f);
  r0[tid] = o2 * Wc[c * 2];
  r1[tid] = o2 * Wc[c * 2 + 1];
  __syncthreads();
  for (int s = 64; s; s >>= 1) {
    if (tid < s) { r0[tid] += r0[tid + s]; r1[tid] += r1[tid + s]; }
    __syncthreads();
  }
  if (tid == 0) {
    atomicAdd(&out[b * NCLS + 0], r0[0]);
    atomicAdd(&out[b * NCLS + 1], r1[0]);
    if (cs == 0) {
      atomicAdd(&out[b * NCLS + 0], bc[0]);
      atomicAdd(&out[b * NCLS + 1], bc[1]);
    }
  }
}

extern "C" void kernel_launch(void* const* d_in, const int* in_sizes, int n_in,
                              void* d_out, int out_size, void* d_ws, size_t ws_size,
                              hipStream_t stream) {
  const float* inputs = (const float*)d_in[0];
  const float* W_feat = (const float*)d_in[1];
  const float* b_feat = (const float*)d_in[2];
  const float* w_enc  = (const float*)d_in[3];
  const float* cls    = (const float*)d_in[5];
  const float* conv_w = (const float*)d_in[6];
  const float* conv_b = (const float*)d_in[7];
  const float* Wq = (const float*)d_in[8];
  const float* bq = (const float*)d_in[9];
  const float* Wk = (const float*)d_in[10];
  const float* bk = (const float*)d_in[11];
  const float* Wv = (const float*)d_in[12];
  const float* bv = (const float*)d_in[13];
  const float* Wo = (const float*)d_in[14];
  const float* bo = (const float*)d_in[15];
  const float* Wc = (const float*)d_in[16];
  const float* bc = (const float*)d_in[17];
  float* out = (float*)d_out;

  char* ws = (char*)d_ws;
  size_t off = 0;
  auto alloc = [&](size_t bytes) -> void* {
    void* p = ws + off;
    off = (off + bytes + 255) & ~(size_t)255;
    return p;
  };
  unsigned short* abf = (unsigned short*)alloc((size_t)MROWS * IND * 2);
  unsigned short* wt  = (unsigned short*)alloc((size_t)HID * IND * 2);
  unsigned short* X   = (unsigned short*)alloc((size_t)MROWS * HID * 2);
  unsigned short* XT  = (unsigned short*)alloc((size_t)BB * NTOK * HID * 2);
  float* u      = (float*)alloc(IND * 4);
  float* slog   = (float*)alloc((size_t)MROWS * 4);
  float* Q      = (float*)alloc(BB * HID * 4);
  float* qvec   = (float*)alloc(BB * HID * 4);
  float* tmat   = (float*)alloc(BB * HEADS * HID * 4);
  float* bkq    = (float*)alloc(BB * HEADS * 4);
  float* logits = (float*)alloc((size_t)BB * HEADS * NTOK * 4);
  float* wsum   = (float*)alloc(BB * HEADS * HID * 4);
  float* Obuf   = (float*)alloc(BB * HID * 4);

  hipMemsetAsync(wsum, 0, BB * HEADS * HID * 4, stream);
  hipMemsetAsync(d_out, 0, (size_t)out_size * 4, stream);

  k_u<<<IND / 4, 256, 0, stream>>>(W_feat, w_enc, u);
  k_wt<<<dim3(IND / 64, HID / 64), 256, 0, stream>>>(W_feat, wt);
  k_cvt<<<MROWS / 4, 256, 0, stream>>>(inputs, u, abf, slog);
  k_gemm<<<dim3(MROWS / 128, HID / 128), 256, 0, stream>>>(abf, wt, b_feat, X);
  k_topq<<<BB, 256, 0, stream>>>(slog, X, Q);
  k_conv<<<dim3((NPIX + 63) / 64, BB), 256, 0, stream>>>(X, Q, conv_w, conv_b, XT);
  k_qprep<<<BB, 256, 0, stream>>>(Q, Wq, bq, Wk, bk, cls, qvec, tmat, bkq, XT);
  k_logits<<<dim3(132, BB), 256, 0, stream>>>(XT, tmat, bkq, logits);
  k_soft<<<BB, 256, 0, stream>>>(logits);
  k_wsum<<<dim3((NTOK + 127) / 128, BB), 256, 0, stream>>>(XT, logits, wsum);
  k_o1<<<16, 128, 0, stream>>>(qvec, wsum, Wv, bv, Obuf);
  k_o2<<<16, 128, 0, stream>>>(Obuf, Wo, bo, Wc, bc, out);
}

// Round 2
// 549.277 us; speedup vs baseline: 1.4394x; 1.4394x over previous
//
#include <hip/hip_runtime.h>
#include <math.h>

#define BB 4
#define NN 8192
#define IND 1024
#define HID 512
#define HEADS 8
#define KSEL 16
#define NCLS 2
#define HH 91
#define NPIX 8281   // 91*91
#define NTOK 8282   // +cls
#define MROWS 32768 // B*N

typedef short short8 __attribute__((ext_vector_type(8)));
typedef float floatx4 __attribute__((ext_vector_type(4)));

__device__ __forceinline__ unsigned short f2bf(float f) {
  union { float f; unsigned u; } v; v.f = f;
  unsigned r = (v.u + 0x7FFFu + ((v.u >> 16) & 1u)) >> 16;
  return (unsigned short)r;
}
__device__ __forceinline__ float bf2f(unsigned short h) {
  union { unsigned u; float f; } v; v.u = ((unsigned)h) << 16;
  return v.f;
}

__device__ __forceinline__ void gld16(const unsigned short* g, void* l) {
  typedef __attribute__((address_space(1))) const void GV;
  typedef __attribute__((address_space(3))) void LV;
  __builtin_amdgcn_global_load_lds((GV*)g, (LV*)l, 16, 0, 0);
}

// ---------------- u = W_feat @ w_enc (fp32, exact scores path) ----------------
__global__ void k_u(const float* __restrict__ W, const float* __restrict__ we,
                    float* __restrict__ u) {
  int wave = threadIdx.x >> 6, lane = threadIdx.x & 63;
  int k = blockIdx.x * 4 + wave;
  const float* wr = W + (long)k * HID + lane * 8;
  const float* wer = we + lane * 8;
  float a = 0.f;
#pragma unroll
  for (int i = 0; i < 8; ++i) a = fmaf(wr[i], wer[i], a);
  for (int off = 32; off; off >>= 1) a += __shfl_down(a, off);
  if (lane == 0) u[k] = a;
}

// ---------------- W_feat -> bf16 transposed [n][k] ----------------
__global__ void k_wt(const float* __restrict__ W, unsigned short* __restrict__ Wt) {
  __shared__ unsigned short s[64][68];
  int kt = blockIdx.x * 64, nt = blockIdx.y * 64;
  int tid = threadIdx.x;
#pragma unroll
  for (int i = 0; i < 16; ++i) {
    int idx = tid + i * 256;
    int kk2 = idx >> 6, nn2 = idx & 63;
    s[nn2][kk2] = f2bf(W[(long)(kt + kk2) * HID + nt + nn2]);
  }
  __syncthreads();
#pragma unroll
  for (int i = 0; i < 16; ++i) {
    int idx = tid + i * 256;
    int nn2 = idx >> 6, kk2 = idx & 63;
    Wt[(long)(nt + nn2) * IND + kt + kk2] = s[nn2][kk2];
  }
}

// ------------- inputs fp32 -> bf16 copy + exact fp32 score logits -------------
__global__ void k_cvt(const float* __restrict__ in, const float* __restrict__ u,
                      unsigned short* __restrict__ abf, float* __restrict__ slog) {
  __shared__ float su[IND];
  int tid = threadIdx.x;
  for (int i = tid; i < IND; i += 256) su[i] = u[i];
  __syncthreads();
  int wave = tid >> 6, lane = tid & 63;
  long row = (long)blockIdx.x * 4 + wave;
  const float* ip = in + row * IND;
  unsigned short* op = abf + row * IND;
  float acc = 0.f;
#pragma unroll
  for (int p = 0; p < 4; ++p) {
    int k = p * 256 + lane * 4;
    float4 v = *(const float4*)(ip + k);
    ushort4 o;
    o.x = f2bf(v.x); o.y = f2bf(v.y); o.z = f2bf(v.z); o.w = f2bf(v.w);
    *(ushort4*)(op + k) = o;
    acc += v.x * su[k] + v.y * su[k + 1] + v.z * su[k + 2] + v.w * su[k + 3];
  }
  for (int off = 32; off; off >>= 1) acc += __shfl_down(acc, off);
  if (lane == 0) slog[row] = acc;
}

// ---------------- GEMM1: x = inputs @ W_feat + b_feat (bf16 MFMA) ----------------
__global__ void k_gemm(const unsigned short* __restrict__ A,
                       const unsigned short* __restrict__ Bt,
                       const float* __restrict__ bias,
                       unsigned short* __restrict__ X) {
  __shared__ unsigned short sA[128 * 32];
  __shared__ unsigned short sB[128 * 32];
  int tid = threadIdx.x;
  int wave = tid >> 6, lane = tid & 63;
  long m0 = (long)blockIdx.x * 128;
  int n0 = blockIdx.y * 128;
  int wm = (wave >> 1) * 64, wn = (wave & 1) * 64;
  int lm = lane & 15, lk = (lane >> 4) * 8;
  floatx4 acc[4][4];
#pragma unroll
  for (int i = 0; i < 4; ++i)
#pragma unroll
    for (int j = 0; j < 4; ++j) acc[i][j] = (floatx4){0.f, 0.f, 0.f, 0.f};

  const unsigned short* gA = A + (m0 + (tid >> 2)) * IND + (tid & 3) * 8;
  const unsigned short* gB = Bt + (long)(n0 + (tid >> 2)) * IND + (tid & 3) * 8;
  char* sAc = (char*)sA + wave * 1024;
  char* sBc = (char*)sB + wave * 1024;

  for (int k0 = 0; k0 < IND; k0 += 32) {
    gld16(gA + k0, sAc);
    gld16(gA + k0 + 64 * IND, sAc + 4096);
    gld16(gB + k0, sBc);
    gld16(gB + k0 + 64 * IND, sBc + 4096);
    __syncthreads();
    short8 af[4], bfr[4];
#pragma unroll
    for (int i = 0; i < 4; ++i)
      af[i] = *(const short8*)(sA + (wm + i * 16 + lm) * 32 + lk);
#pragma unroll
    for (int j = 0; j < 4; ++j)
      bfr[j] = *(const short8*)(sB + (wn + j * 16 + lm) * 32 + lk);
#pragma unroll
    for (int i = 0; i < 4; ++i)
#pragma unroll
      for (int j = 0; j < 4; ++j)
        acc[i][j] = __builtin_amdgcn_mfma_f32_16x16x32_bf16(af[i], bfr[j], acc[i][j], 0, 0, 0);
    __syncthreads();
  }
#pragma unroll
  for (int j = 0; j < 4; ++j) {
    int gcol = n0 + wn + j * 16 + lm;
    float bv_ = bias[gcol];
#pragma unroll
    for (int i = 0; i < 4; ++i) {
      long grow = m0 + wm + i * 16 + (lane >> 4) * 4;
#pragma unroll
      for (int r = 0; r < 4; ++r)
        X[(grow + r) * HID + gcol] = f2bf(acc[i][j][r] + bv_);
    }
  }
}

// ---------------- top-K (exact fp32 scores) + Q = mean of selected rows ----------------
__global__ void k_topq(const float* __restrict__ slog, const unsigned short* __restrict__ X,
                       float* __restrict__ Q) {
  __shared__ float sc[NN];
  __shared__ float rv[256];
  __shared__ int ri[256];
  __shared__ int wi[KSEL];
  int b = blockIdx.x, tid = threadIdx.x;
  for (int i = tid; i < NN; i += 256) sc[i] = slog[b * NN + i];
  __syncthreads();
  for (int it = 0; it < KSEL; ++it) {
    float bv = -3.4e38f; int bi = 0x7FFFFFFF;
    for (int i = tid; i < NN; i += 256) {
      float v = sc[i];
      if (v > bv) { bv = v; bi = i; }
    }
    rv[tid] = bv; ri[tid] = bi;
    __syncthreads();
    for (int s = 128; s; s >>= 1) {
      if (tid < s) {
        float v2 = rv[tid + s]; int i2 = ri[tid + s];
        if (v2 > rv[tid] || (v2 == rv[tid] && i2 < ri[tid])) { rv[tid] = v2; ri[tid] = i2; }
      }
      __syncthreads();
    }
    if (tid == 0) { wi[it] = ri[0]; sc[ri[0]] = -3.4e38f; }
    __syncthreads();
  }
  for (int c = tid; c < HID; c += 256) {
    float s = 0.f;
    for (int t2 = 0; t2 < KSEL; ++t2)
      s += bf2f(X[((long)b * NN + wi[t2]) * HID + c]);
    Q[b * HID + c] = s * (1.f / KSEL);
  }
}

// ------- x2 = relu(x - Q); depthwise 3x3 conv (SAME) + conv_b + residual -> x̃ rows 1.. -------
// 8 pixels per block (serial), 256 threads = 256 channel-pairs, massive grid.
__global__ void k_conv(const unsigned short* __restrict__ X, const float* __restrict__ Q,
                       const float* __restrict__ cw, const float* __restrict__ cb,
                       unsigned short* __restrict__ XT) {
  int tid = threadIdx.x;
  int b = blockIdx.y;
  int c = tid * 2;
  float w0[9], w1[9];
#pragma unroll
  for (int t = 0; t < 9; ++t) { w0[t] = cw[c * 9 + t]; w1[t] = cw[(c + 1) * 9 + t]; }
  float q0 = Q[b * HID + c], q1 = Q[b * HID + c + 1];
  float cb0 = cb[c], cb1 = cb[c + 1];
  int nbase = blockIdx.x * 8;
  const unsigned short* xb = X + (long)b * NN * HID;
#pragma unroll
  for (int ii = 0; ii < 8; ++ii) {
    int n = nbase + ii;
    if (n >= NPIX) break;
    int h = n / HH, w = n - h * HH;
    float a0 = 0.f, a1 = 0.f, c0v = 0.f, c1v = 0.f;
#pragma unroll
    for (int dy = 0; dy < 3; ++dy) {
      int hh2 = h + dy - 1;
      if (hh2 < 0 || hh2 >= HH) continue;
#pragma unroll
      for (int dx = 0; dx < 3; ++dx) {
        int ww2 = w + dx - 1;
        if (ww2 < 0 || ww2 >= HH) continue;
        int n2 = hh2 * HH + ww2;
        int r = n2 < NN ? n2 : n2 - NN;
        unsigned v = *(const unsigned*)(xb + (long)r * HID + c);
        float f0 = bf2f((unsigned short)(v & 0xFFFF));
        float f1 = bf2f((unsigned short)(v >> 16));
        f0 = fmaxf(f0 - q0, 0.f);
        f1 = fmaxf(f1 - q1, 0.f);
        int t = dy * 3 + dx;
        a0 = fmaf(w0[t], f0, a0);
        a1 = fmaf(w1[t], f1, a1);
        if (t == 4) { c0v = f0; c1v = f1; }
      }
    }
    unsigned out = (unsigned)f2bf(a0 + cb0 + c0v) | ((unsigned)f2bf(a1 + cb1 + c1v) << 16);
    *(unsigned*)(XT + ((long)b * NTOK + 1 + n) * HID + c) = out;
  }
}

// ---------------- qvec = Q@Wq + bq (64 cols per block); cls row of x̃ ----------------
__global__ void k_qv(const float* __restrict__ Q, const float* __restrict__ Wq,
                     const float* __restrict__ bq, const float* __restrict__ cls,
                     float* __restrict__ qvec, unsigned short* __restrict__ XT) {
  __shared__ float sq[HID];
  __shared__ float part[4][64];
  int b = blockIdx.y, cblk = blockIdx.x, tid = threadIdx.x;
  for (int i = tid; i < HID; i += 256) sq[i] = Q[b * HID + i];
  __syncthreads();
  int cl = tid & 63, seg = tid >> 6;
  int c = cblk * 64 + cl;
  float a = 0.f;
#pragma unroll 8
  for (int j = seg * 128; j < seg * 128 + 128; ++j)
    a = fmaf(sq[j], Wq[(long)j * HID + c], a);
  part[seg][cl] = a;
  __syncthreads();
  if (seg == 0)
    qvec[b * HID + c] = part[0][cl] + part[1][cl] + part[2][cl] + part[3][cl] + bq[c];
  if (cblk == 0)
    for (int i = tid; i < HID; i += 256)
      XT[(long)b * NTOK * HID + i] = f2bf(cls[i]);
}

// ---------------- t[b,h,j] = sum_d Wk[j, h*64+d] * q[h,d];  bkq[b,h] ----------------
__global__ void k_tprep(const float* __restrict__ qvec, const float* __restrict__ Wk,
                        const float* __restrict__ bk, float* __restrict__ tmat,
                        float* __restrict__ bkq) {
  __shared__ float qh[64];
  int b = blockIdx.y, h = blockIdx.x, tid = threadIdx.x;
  if (tid < 64) qh[tid] = qvec[b * HID + h * 64 + tid];
  __syncthreads();
  int d = tid & 63, jg = tid >> 6;
  float qd = qh[d];
  for (int jj = 0; jj < 128; ++jj) {
    int j = jj * 4 + jg;
    float v = Wk[(long)j * HID + h * 64 + d] * qd;
    for (int off = 32; off; off >>= 1) v += __shfl_down(v, off);
    if (d == 0) tmat[((long)b * HEADS + h) * HID + j] = v;
  }
  if (tid < 64) {
    float v = bk[h * 64 + tid] * qh[tid];
    for (int off = 32; off; off >>= 1) v += __shfl_down(v, off);
    if (tid == 0) bkq[b * HEADS + h] = v;
  }
}

// ---------------- logits[b,h,n] = (x̃[n]·t[h] + bkq[h]) / sqrt(512) ----------------
__global__ void k_logits(const unsigned short* __restrict__ XT, const float* __restrict__ tmat,
                         const float* __restrict__ bkq, float* __restrict__ logits) {
  __shared__ float st[HEADS * HID];
  __shared__ float sb[HEADS];
  int b = blockIdx.y, tid = threadIdx.x;
  for (int i = tid; i < HEADS * HID; i += 256) st[i] = tmat[(long)b * HEADS * HID + i];
  if (tid < HEADS) sb[tid] = bkq[b * HEADS + tid];
  __syncthreads();
  int wave = tid >> 6, lane = tid & 63;
  float tr[HEADS][8];
#pragma unroll
  for (int h = 0; h < HEADS; ++h)
#pragma unroll
    for (int i = 0; i < 8; ++i) tr[h][i] = st[h * HID + lane * 8 + i];
  float sbr[HEADS];
#pragma unroll
  for (int h = 0; h < HEADS; ++h) sbr[h] = sb[h];

  for (long row = blockIdx.x * 4 + wave; row < NTOK; row += 4L * gridDim.x) {
    const unsigned short* xr = XT + ((long)b * NTOK + row) * HID + lane * 8;
    ushort4 v0 = *(const ushort4*)xr;
    ushort4 v1 = *(const ushort4*)(xr + 4);
    float xf[8] = {bf2f(v0.x), bf2f(v0.y), bf2f(v0.z), bf2f(v0.w),
                   bf2f(v1.x), bf2f(v1.y), bf2f(v1.z), bf2f(v1.w)};
    float acc[HEADS];
#pragma unroll
    for (int h = 0; h < HEADS; ++h) {
      float a = 0.f;
#pragma unroll
      for (int i = 0; i < 8; ++i) a = fmaf(xf[i], tr[h][i], a);
      acc[h] = a;
    }
#pragma unroll
    for (int h = 0; h < HEADS; ++h)
      for (int off = 32; off; off >>= 1) acc[h] += __shfl_down(acc[h], off);
    if (lane == 0) {
#pragma unroll
      for (int h = 0; h < HEADS; ++h)
        logits[((long)b * HEADS + h) * NTOK + row] = (acc[h] + sbr[h]) * 0.044194173824159216f;
    }
  }
}

// ---------------- softmax, one block per (b,h), LDS-staged ----------------
__global__ void k_soft(float* __restrict__ logits) {
  __shared__ float sl[NTOK];
  __shared__ float red[256];
  int bh = blockIdx.x, tid = threadIdx.x;
  float* lp = logits + (long)bh * NTOK;
  for (int i = tid; i < NTOK; i += 256) sl[i] = lp[i];
  __syncthreads();
  float m = -3.4e38f;
  for (int i = tid; i < NTOK; i += 256) m = fmaxf(m, sl[i]);
  red[tid] = m; __syncthreads();
  for (int s = 128; s; s >>= 1) { if (tid < s) red[tid] = fmaxf(red[tid], red[tid + s]); __syncthreads(); }
  m = red[0]; __syncthreads();
  float sm = 0.f;
  for (int i = tid; i < NTOK; i += 256) {
    float e = __expf(sl[i] - m);
    sl[i] = e;
    sm += e;
  }
  red[tid] = sm; __syncthreads();
  for (int s = 128; s; s >>= 1) { if (tid < s) red[tid] += red[tid + s]; __syncthreads(); }
  float inv = 1.f / red[0];
  __syncthreads();
  for (int i = tid; i < NTOK; i += 256) lp[i] = sl[i] * inv;
}

// ---------------- wsum[b,h,:] = sum_n P[h,n] * x̃[n,:] ----------------
__global__ void k_wsum(const unsigned short* __restrict__ XT, const float* __restrict__ P,
                       float* __restrict__ wsum) {
  __shared__ float pw[HEADS * 64];
  int b = blockIdx.y, tid = threadIdx.x;
  int nbase = blockIdx.x * 64;
  for (int i = tid; i < HEADS * 64; i += 256) {
    int h = i >> 6, nn = i & 63;
    long n = nbase + nn;
    pw[i] = (n < NTOK) ? P[((long)b * HEADS + h) * NTOK + n] : 0.f;
  }
  __syncthreads();
  int c = tid * 2;
  float wa[HEADS][2];
#pragma unroll
  for (int h = 0; h < HEADS; ++h) { wa[h][0] = 0.f; wa[h][1] = 0.f; }
  int lim = NTOK - nbase; if (lim > 64) lim = 64;
  for (int nn = 0; nn < lim; ++nn) {
    unsigned v = *(const unsigned*)(XT + ((long)b * NTOK + nbase + nn) * HID + c);
    float f0 = bf2f((unsigned short)(v & 0xFFFF));
    float f1 = bf2f((unsigned short)(v >> 16));
#pragma unroll
    for (int h = 0; h < HEADS; ++h) {
      float p = pw[h * 64 + nn];
      wa[h][0] = fmaf(p, f0, wa[h][0]);
      wa[h][1] = fmaf(p, f1, wa[h][1]);
    }
  }
#pragma unroll
  for (int h = 0; h < HEADS; ++h) {
    atomicAdd(&wsum[((long)b * HEADS + h) * HID + c], wa[h][0]);
    atomicAdd(&wsum[((long)b * HEADS + h) * HID + c + 1], wa[h][1]);
  }
}

// ---------------- Opart[b,c] = sum_j wsum[b,h(c),j] * Wv[j,c]  (split-K) ----------------
__global__ void k_o1(const float* __restrict__ wsum, const float* __restrict__ Wv,
                     float* __restrict__ Opart) {
  __shared__ float part[2][128];
  int cblk = blockIdx.x, kc = blockIdx.y, b = blockIdx.z;
  int tid = threadIdx.x;
  int cl = tid & 127, seg = tid >> 7;
  int c = cblk * 128 + cl;
  int h = c >> 6;
  const float* wp = wsum + ((long)b * HEADS + h) * HID;
  int j0 = kc * 64 + seg * 32;
  float a = 0.f;
#pragma unroll 8
  for (int j = j0; j < j0 + 32; ++j) a = fmaf(wp[j], Wv[(long)j * HID + c], a);
  part[seg][cl] = a;
  __syncthreads();
  if (seg == 0) atomicAdd(&Opart[b * HID + c], part[0][cl] + part[1][cl]);
}

// ---------------- t2[b,c] = sum_j so[j]*Wo[j,c], so = qvec+bv+Opart (split-K) ----------------
__global__ void k_o2a(const float* __restrict__ qvec, const float* __restrict__ bv,
                      const float* __restrict__ Opart, const float* __restrict__ Wo,
                      float* __restrict__ t2) {
  __shared__ float part[2][128];
  int cblk = blockIdx.x, kc = blockIdx.y, b = blockIdx.z;
  int tid = threadIdx.x;
  int cl = tid & 127, seg = tid >> 7;
  int c = cblk * 128 + cl;
  int j0 = kc * 64 + seg * 32;
  float a = 0.f;
#pragma unroll 8
  for (int j = j0; j < j0 + 32; ++j) {
    float so = qvec[b * HID + j] + bv[j] + Opart[b * HID + j];
    a = fmaf(so, Wo[(long)j * HID + c], a);
  }
  part[seg][cl] = a;
  __syncthreads();
  if (seg == 0) atomicAdd(&t2[b * HID + c], part[0][cl] + part[1][cl]);
}

// ---------------- o2 = so + relu(t2+bo);  out = o2@Wc + bc ----------------
__global__ void k_o2b(const float* __restrict__ qvec, const float* __restrict__ bv,
                      const float* __restrict__ Opart, const float* __restrict__ bo,
                      const float* __restrict__ t2, const float* __restrict__ Wc,
                      const float* __restrict__ bc, float* __restrict__ out) {
  __shared__ float r0[256], r1[256];
  int b = blockIdx.x, tid = threadIdx.x;
  float s0 = 0.f, s1 = 0.f;
  for (int c = tid; c < HID; c += 256) {
    float so = qvec[b * HID + c] + bv[c] + Opart[b * HID + c];
    float o2 = so + fmaxf(t2[b * HID + c] + bo[c], 0.f);
    s0 = fmaf(o2, Wc[c * 2], s0);
    s1 = fmaf(o2, Wc[c * 2 + 1], s1);
  }
  r0[tid] = s0; r1[tid] = s1;
  __syncthreads();
  for (int s = 128; s; s >>= 1) {
    if (tid < s) { r0[tid] += r0[tid + s]; r1[tid] += r1[tid + s]; }
    __syncthreads();
  }
  if (tid == 0) {
    out[b * NCLS + 0] = r0[0] + bc[0];
    out[b * NCLS + 1] = r1[0] + bc[1];
  }
}

extern "C" void kernel_launch(void* const* d_in, const int* in_sizes, int n_in,
                              void* d_out, int out_size, void* d_ws, size_t ws_size,
                              hipStream_t stream) {
  const float* inputs = (const float*)d_in[0];
  const float* W_feat = (const float*)d_in[1];
  const float* b_feat = (const float*)d_in[2];
  const float* w_enc  = (const float*)d_in[3];
  const float* cls    = (const float*)d_in[5];
  const float* conv_w = (const float*)d_in[6];
  const float* conv_b = (const float*)d_in[7];
  const float* Wq = (const float*)d_in[8];
  const float* bq = (const float*)d_in[9];
  const float* Wk = (const float*)d_in[10];
  const float* bk = (const float*)d_in[11];
  const float* Wv = (const float*)d_in[12];
  const float* bv = (const float*)d_in[13];
  const float* Wo = (const float*)d_in[14];
  const float* bo = (const float*)d_in[15];
  const float* Wc = (const float*)d_in[16];
  const float* bc = (const float*)d_in[17];
  float* out = (float*)d_out;

  char* ws = (char*)d_ws;
  size_t off = 0;
  auto alloc = [&](size_t bytes) -> void* {
    void* p = ws + off;
    off = (off + bytes + 255) & ~(size_t)255;
    return p;
  };
  unsigned short* abf = (unsigned short*)alloc((size_t)MROWS * IND * 2);
  unsigned short* wt  = (unsigned short*)alloc((size_t)HID * IND * 2);
  unsigned short* X   = (unsigned short*)alloc((size_t)MROWS * HID * 2);
  unsigned short* XT  = (unsigned short*)alloc((size_t)BB * NTOK * HID * 2);
  float* u      = (float*)alloc(IND * 4);
  float* slog   = (float*)alloc((size_t)MROWS * 4);
  float* Q      = (float*)alloc(BB * HID * 4);
  float* qvec   = (float*)alloc(BB * HID * 4);
  float* tmat   = (float*)alloc(BB * HEADS * HID * 4);
  float* bkq    = (float*)alloc(BB * HEADS * 4);
  float* logits = (float*)alloc((size_t)BB * HEADS * NTOK * 4);
  float* wsum   = (float*)alloc(BB * HEADS * HID * 4);
  float* Opart  = (float*)alloc(BB * HID * 4);
  float* t2buf  = (float*)alloc(BB * HID * 4);

  hipMemsetAsync(wsum, 0, BB * HEADS * HID * 4, stream);
  hipMemsetAsync(Opart, 0, BB * HID * 4, stream);
  hipMemsetAsync(t2buf, 0, BB * HID * 4, stream);

  k_u<<<IND / 4, 256, 0, stream>>>(W_feat, w_enc, u);
  k_wt<<<dim3(IND / 64, HID / 64), 256, 0, stream>>>(W_feat, wt);
  k_cvt<<<MROWS / 4, 256, 0, stream>>>(inputs, u, abf, slog);
  k_gemm<<<dim3(MROWS / 128, HID / 128), 256, 0, stream>>>(abf, wt, b_feat, X);
  k_topq<<<BB, 256, 0, stream>>>(slog, X, Q);
  k_conv<<<dim3((NPIX + 7) / 8, BB), 256, 0, stream>>>(X, Q, conv_w, conv_b, XT);
  k_qv<<<dim3(HID / 64, BB), 256, 0, stream>>>(Q, Wq, bq, cls, qvec, XT);
  k_tprep<<<dim3(HEADS, BB), 256, 0, stream>>>(qvec, Wk, bk, tmat, bkq);
  k_logits<<<dim3(132, BB), 256, 0, stream>>>(XT, tmat, bkq, logits);
  k_soft<<<BB * HEADS, 256, 0, stream>>>(logits);
  k_wsum<<<dim3((NTOK + 63) / 64, BB), 256, 0, stream>>>(XT, logits, wsum);
  k_o1<<<dim3(HID / 128, 8, BB), 256, 0, stream>>>(wsum, Wv, Opart);
  k_o2a<<<dim3(HID / 128, 8, BB), 256, 0, stream>>>(qvec, bv, Opart, Wo, t2buf);
  k_o2b<<<BB, 256, 0, stream>>>(qvec, bv, Opart, bo, t2buf, Wc, bc, out);
}

// Round 3
// 540.403 us; speedup vs baseline: 1.4630x; 1.0164x over previous
//
#include <hip/hip_runtime.h>
#include <math.h>

#define BB 4
#define NN 8192
#define IND 1024
#define HID 512
#define HEADS 8
#define KSEL 16
#define NCLS 2
#define HH 91
#define NPIX 8281   // 91*91
#define NTOK 8282   // +cls
#define MROWS 32768 // B*N

typedef short short8 __attribute__((ext_vector_type(8)));
typedef float floatx4 __attribute__((ext_vector_type(4)));

__device__ __forceinline__ unsigned short f2bf(float f) {
  union { float f; unsigned u; } v; v.f = f;
  unsigned r = (v.u + 0x7FFFu + ((v.u >> 16) & 1u)) >> 16;
  return (unsigned short)r;
}
__device__ __forceinline__ float bf2f(unsigned short h) {
  union { unsigned u; float f; } v; v.u = ((unsigned)h) << 16;
  return v.f;
}

__device__ __forceinline__ void gld16(const unsigned short* g, void* l) {
  typedef __attribute__((address_space(1))) const void GV;
  typedef __attribute__((address_space(3))) void LV;
  __builtin_amdgcn_global_load_lds((GV*)g, (LV*)l, 16, 0, 0);
}

// ---------------- u = W_feat @ w_enc (fp32, exact scores path) ----------------
__global__ void k_u(const float* __restrict__ W, const float* __restrict__ we,
                    float* __restrict__ u) {
  int wave = threadIdx.x >> 6, lane = threadIdx.x & 63;
  int k = blockIdx.x * 4 + wave;
  const float* wr = W + (long)k * HID + lane * 8;
  const float* wer = we + lane * 8;
  float a = 0.f;
#pragma unroll
  for (int i = 0; i < 8; ++i) a = fmaf(wr[i], wer[i], a);
  for (int off = 32; off; off >>= 1) a += __shfl_down(a, off);
  if (lane == 0) u[k] = a;
}

// ---------------- W_feat -> bf16 transposed [n][k] ----------------
__global__ void k_wt(const float* __restrict__ W, unsigned short* __restrict__ Wt) {
  __shared__ unsigned short s[64][68];
  int kt = blockIdx.x * 64, nt = blockIdx.y * 64;
  int tid = threadIdx.x;
#pragma unroll
  for (int i = 0; i < 16; ++i) {
    int idx = tid + i * 256;
    int kk2 = idx >> 6, nn2 = idx & 63;
    s[nn2][kk2] = f2bf(W[(long)(kt + kk2) * HID + nt + nn2]);
  }
  __syncthreads();
#pragma unroll
  for (int i = 0; i < 16; ++i) {
    int idx = tid + i * 256;
    int nn2 = idx >> 6, kk2 = idx & 63;
    Wt[(long)(nt + nn2) * IND + kt + kk2] = s[nn2][kk2];
  }
}

// ------------- inputs fp32 -> bf16 copy + exact fp32 score logits -------------
__global__ void k_cvt(const float* __restrict__ in, const float* __restrict__ u,
                      unsigned short* __restrict__ abf, float* __restrict__ slog) {
  __shared__ float su[IND];
  int tid = threadIdx.x;
  for (int i = tid; i < IND; i += 256) su[i] = u[i];
  __syncthreads();
  int wave = tid >> 6, lane = tid & 63;
  long row = (long)blockIdx.x * 4 + wave;
  const float* ip = in + row * IND;
  unsigned short* op = abf + row * IND;
  float acc = 0.f;
#pragma unroll
  for (int p = 0; p < 4; ++p) {
    int k = p * 256 + lane * 4;
    float4 v = *(const float4*)(ip + k);
    ushort4 o;
    o.x = f2bf(v.x); o.y = f2bf(v.y); o.z = f2bf(v.z); o.w = f2bf(v.w);
    *(ushort4*)(op + k) = o;
    acc += v.x * su[k] + v.y * su[k + 1] + v.z * su[k + 2] + v.w * su[k + 3];
  }
  for (int off = 32; off; off >>= 1) acc += __shfl_down(acc, off);
  if (lane == 0) slog[row] = acc;
}

// ------- GEMM1: x = inputs @ W_feat + b_feat (bf16 MFMA, 128x256 tile, 8 waves) -------
__global__ __launch_bounds__(512) void k_gemm(const unsigned short* __restrict__ A,
                                              const unsigned short* __restrict__ Bt,
                                              const float* __restrict__ bias,
                                              unsigned short* __restrict__ X) {
  __shared__ unsigned short sA[128 * 32];
  __shared__ unsigned short sB[256 * 32];
  int tid = threadIdx.x;
  int wave = tid >> 6, lane = tid & 63;
  long m0 = (long)blockIdx.x * 128;
  int n0 = blockIdx.y * 256;
  int wm = (wave >> 2) * 64, wn = (wave & 3) * 64;
  int lm = lane & 15, lk = (lane >> 4) * 8;
  floatx4 acc[4][4];
#pragma unroll
  for (int i = 0; i < 4; ++i)
#pragma unroll
    for (int j = 0; j < 4; ++j) acc[i][j] = (floatx4){0.f, 0.f, 0.f, 0.f};

  const unsigned short* gA = A + (m0 + (tid >> 2)) * IND + (tid & 3) * 8;
  const unsigned short* gB = Bt + (long)(n0 + (tid >> 2)) * IND + (tid & 3) * 8;
  char* sAc = (char*)sA + wave * 1024;
  char* sBc = (char*)sB + wave * 1024;

  for (int k0 = 0; k0 < IND; k0 += 32) {
    gld16(gA + k0, sAc);
    gld16(gB + k0, sBc);
    gld16(gB + k0 + 128 * IND, sBc + 8192);
    __syncthreads();
    short8 af[4], bfr[4];
#pragma unroll
    for (int i = 0; i < 4; ++i)
      af[i] = *(const short8*)(sA + (wm + i * 16 + lm) * 32 + lk);
#pragma unroll
    for (int j = 0; j < 4; ++j)
      bfr[j] = *(const short8*)(sB + (wn + j * 16 + lm) * 32 + lk);
#pragma unroll
    for (int i = 0; i < 4; ++i)
#pragma unroll
      for (int j = 0; j < 4; ++j)
        acc[i][j] = __builtin_amdgcn_mfma_f32_16x16x32_bf16(af[i], bfr[j], acc[i][j], 0, 0, 0);
    __syncthreads();
  }
#pragma unroll
  for (int j = 0; j < 4; ++j) {
    int gcol = n0 + wn + j * 16 + lm;
    float bv_ = bias[gcol];
#pragma unroll
    for (int i = 0; i < 4; ++i) {
      long grow = m0 + wm + i * 16 + (lane >> 4) * 4;
#pragma unroll
      for (int r = 0; r < 4; ++r)
        X[(grow + r) * HID + gcol] = f2bf(acc[i][j][r] + bv_);
    }
  }
}

// ------- top-K (exact fp32 scores), 1024 thr, wave-shuffle reduce; Q = mean -------
__global__ __launch_bounds__(1024) void k_topq(const float* __restrict__ slog,
                                               const unsigned short* __restrict__ X,
                                               float* __restrict__ Q) {
  __shared__ float sc[NN];
  __shared__ float wvs[16];
  __shared__ int wis[16];
  __shared__ int wi[KSEL];
  int b = blockIdx.x, tid = threadIdx.x;
  int lane = tid & 63, wid = tid >> 6;
  for (int i = tid; i < NN; i += 1024) sc[i] = slog[b * NN + i];
  __syncthreads();
  for (int it = 0; it < KSEL; ++it) {
    float bv = -3.4e38f; int bi = 0x7FFFFFFF;
#pragma unroll
    for (int r = 0; r < 8; ++r) {
      int i = tid + r * 1024;
      float v = sc[i];
      if (v > bv || (v == bv && i < bi)) { bv = v; bi = i; }
    }
    for (int off = 32; off; off >>= 1) {
      float v2 = __shfl_down(bv, off);
      int i2 = __shfl_down(bi, off);
      if (v2 > bv || (v2 == bv && i2 < bi)) { bv = v2; bi = i2; }
    }
    if (lane == 0) { wvs[wid] = bv; wis[wid] = bi; }
    __syncthreads();
    if (tid == 0) {
      float best = wvs[0]; int besti = wis[0];
#pragma unroll
      for (int w = 1; w < 16; ++w)
        if (wvs[w] > best || (wvs[w] == best && wis[w] < besti)) { best = wvs[w]; besti = wis[w]; }
      wi[it] = besti;
      sc[besti] = -3.4e38f;
    }
    __syncthreads();
  }
  if (tid < HID) {
    float s = 0.f;
#pragma unroll
    for (int t2 = 0; t2 < KSEL; ++t2)
      s += bf2f(X[((long)b * NN + wi[t2]) * HID + tid]);
    Q[b * HID + tid] = s * (1.f / KSEL);
  }
}

// ------- x2 = relu(x - Q); depthwise 3x3 conv (SAME) + conv_b + residual -> x̃ rows 1.. -------
__global__ void k_conv(const unsigned short* __restrict__ X, const float* __restrict__ Q,
                       const float* __restrict__ cw, const float* __restrict__ cb,
                       unsigned short* __restrict__ XT) {
  int tid = threadIdx.x;
  int b = blockIdx.y;
  int c = tid * 2;
  float w0[9], w1[9];
#pragma unroll
  for (int t = 0; t < 9; ++t) { w0[t] = cw[c * 9 + t]; w1[t] = cw[(c + 1) * 9 + t]; }
  float q0 = Q[b * HID + c], q1 = Q[b * HID + c + 1];
  float cb0 = cb[c], cb1 = cb[c + 1];
  int nbase = blockIdx.x * 8;
  const unsigned short* xb = X + (long)b * NN * HID;
#pragma unroll
  for (int ii = 0; ii < 8; ++ii) {
    int n = nbase + ii;
    if (n >= NPIX) break;
    int h = n / HH, w = n - h * HH;
    float a0 = 0.f, a1 = 0.f, c0v = 0.f, c1v = 0.f;
#pragma unroll
    for (int dy = 0; dy < 3; ++dy) {
      int hh2 = h + dy - 1;
      if (hh2 < 0 || hh2 >= HH) continue;
#pragma unroll
      for (int dx = 0; dx < 3; ++dx) {
        int ww2 = w + dx - 1;
        if (ww2 < 0 || ww2 >= HH) continue;
        int n2 = hh2 * HH + ww2;
        int r = n2 < NN ? n2 : n2 - NN;
        unsigned v = *(const unsigned*)(xb + (long)r * HID + c);
        float f0 = bf2f((unsigned short)(v & 0xFFFF));
        float f1 = bf2f((unsigned short)(v >> 16));
        f0 = fmaxf(f0 - q0, 0.f);
        f1 = fmaxf(f1 - q1, 0.f);
        int t = dy * 3 + dx;
        a0 = fmaf(w0[t], f0, a0);
        a1 = fmaf(w1[t], f1, a1);
        if (t == 4) { c0v = f0; c1v = f1; }
      }
    }
    unsigned out = (unsigned)f2bf(a0 + cb0 + c0v) | ((unsigned)f2bf(a1 + cb1 + c1v) << 16);
    *(unsigned*)(XT + ((long)b * NTOK + 1 + n) * HID + c) = out;
  }
}

// ------- merged: qvec cols for head h; t[b,h,:]; bkq; cls row -------
__global__ void k_qkprep(const float* __restrict__ Q, const float* __restrict__ Wq,
                         const float* __restrict__ bq, const float* __restrict__ Wk,
                         const float* __restrict__ bk, const float* __restrict__ cls,
                         float* __restrict__ qvec, float* __restrict__ tmat,
                         float* __restrict__ bkq, unsigned short* __restrict__ XT) {
  __shared__ float sq[HID];
  __shared__ float part[4][64];
  __shared__ float qh[64];
  int h = blockIdx.x, b = blockIdx.y, tid = threadIdx.x;
  for (int i = tid; i < HID; i += 256) sq[i] = Q[b * HID + i];
  __syncthreads();
  int cl = tid & 63, seg = tid >> 6;
  int c = h * 64 + cl;
  float a = 0.f;
#pragma unroll 8
  for (int j = seg * 128; j < seg * 128 + 128; ++j)
    a = fmaf(sq[j], Wq[(long)j * HID + c], a);
  part[seg][cl] = a;
  __syncthreads();
  if (seg == 0) {
    float q = part[0][cl] + part[1][cl] + part[2][cl] + part[3][cl] + bq[c];
    qvec[b * HID + c] = q;
    qh[cl] = q;
  }
  __syncthreads();
  int d = tid & 63, jg = tid >> 6;
  float qd = qh[d];
  for (int jj = 0; jj < 128; ++jj) {
    int j = jj * 4 + jg;
    float v = Wk[(long)j * HID + h * 64 + d] * qd;
    for (int off = 32; off; off >>= 1) v += __shfl_down(v, off);
    if (d == 0) tmat[((long)b * HEADS + h) * HID + j] = v;
  }
  if (tid < 64) {
    float v = bk[h * 64 + tid] * qh[tid];
    for (int off = 32; off; off >>= 1) v += __shfl_down(v, off);
    if (tid == 0) bkq[b * HEADS + h] = v;
  }
  if (h == 0)
    for (int i = tid; i < HID; i += 256)
      XT[(long)b * NTOK * HID + i] = f2bf(cls[i]);
}

// ---------------- logits[b,h,n] = (x̃[n]·t[h] + bkq[h]) / sqrt(512) ----------------
__global__ void k_logits(const unsigned short* __restrict__ XT, const float* __restrict__ tmat,
                         const float* __restrict__ bkq, float* __restrict__ logits) {
  __shared__ float st[HEADS * HID];
  __shared__ float sb[HEADS];
  int b = blockIdx.y, tid = threadIdx.x;
  for (int i = tid; i < HEADS * HID; i += 256) st[i] = tmat[(long)b * HEADS * HID + i];
  if (tid < HEADS) sb[tid] = bkq[b * HEADS + tid];
  __syncthreads();
  int wave = tid >> 6, lane = tid & 63;
  float tr[HEADS][8];
#pragma unroll
  for (int h = 0; h < HEADS; ++h)
#pragma unroll
    for (int i = 0; i < 8; ++i) tr[h][i] = st[h * HID + lane * 8 + i];
  float sbr[HEADS];
#pragma unroll
  for (int h = 0; h < HEADS; ++h) sbr[h] = sb[h];

  for (long row = blockIdx.x * 4 + wave; row < NTOK; row += 4L * gridDim.x) {
    const unsigned short* xr = XT + ((long)b * NTOK + row) * HID + lane * 8;
    ushort4 v0 = *(const ushort4*)xr;
    ushort4 v1 = *(const ushort4*)(xr + 4);
    float xf[8] = {bf2f(v0.x), bf2f(v0.y), bf2f(v0.z), bf2f(v0.w),
                   bf2f(v1.x), bf2f(v1.y), bf2f(v1.z), bf2f(v1.w)};
    float acc[HEADS];
#pragma unroll
    for (int h = 0; h < HEADS; ++h) {
      float a = 0.f;
#pragma unroll
      for (int i = 0; i < 8; ++i) a = fmaf(xf[i], tr[h][i], a);
      acc[h] = a;
    }
#pragma unroll
    for (int h = 0; h < HEADS; ++h)
      for (int off = 32; off; off >>= 1) acc[h] += __shfl_down(acc[h], off);
    if (lane == 0) {
#pragma unroll
      for (int h = 0; h < HEADS; ++h)
        logits[((long)b * HEADS + h) * NTOK + row] = (acc[h] + sbr[h]) * 0.044194173824159216f;
    }
  }
}

// ------- softmax, one block per (b,h); also zero-inits wsum/Opart/t2 slices -------
__global__ void k_soft(float* __restrict__ logits, float* __restrict__ wsum,
                       float* __restrict__ Opart, float* __restrict__ t2) {
  __shared__ float sl[NTOK];
  __shared__ float red[256];
  int bh = blockIdx.x, tid = threadIdx.x;
  int b = bh >> 3, h = bh & 7;
  for (int i = tid; i < HID; i += 256) wsum[(long)bh * HID + i] = 0.f;
  if (tid < 64) {
    Opart[b * HID + h * 64 + tid] = 0.f;
    t2[b * HID + h * 64 + tid] = 0.f;
  }
  float* lp = logits + (long)bh * NTOK;
  for (int i = tid; i < NTOK; i += 256) sl[i] = lp[i];
  __syncthreads();
  float m = -3.4e38f;
  for (int i = tid; i < NTOK; i += 256) m = fmaxf(m, sl[i]);
  red[tid] = m; __syncthreads();
  for (int s = 128; s; s >>= 1) { if (tid < s) red[tid] = fmaxf(red[tid], red[tid + s]); __syncthreads(); }
  m = red[0]; __syncthreads();
  float sm = 0.f;
  for (int i = tid; i < NTOK; i += 256) {
    float e = __expf(sl[i] - m);
    sl[i] = e;
    sm += e;
  }
  red[tid] = sm; __syncthreads();
  for (int s = 128; s; s >>= 1) { if (tid < s) red[tid] += red[tid + s]; __syncthreads(); }
  float inv = 1.f / red[0];
  __syncthreads();
  for (int i = tid; i < NTOK; i += 256) lp[i] = sl[i] * inv;
}

// ---------------- wsum[b,h,:] = sum_n P[h,n] * x̃[n,:] ----------------
__global__ void k_wsum(const unsigned short* __restrict__ XT, const float* __restrict__ P,
                       float* __restrict__ wsum) {
  __shared__ float pw[HEADS * 64];
  int b = blockIdx.y, tid = threadIdx.x;
  int nbase = blockIdx.x * 64;
  for (int i = tid; i < HEADS * 64; i += 256) {
    int h = i >> 6, nn = i & 63;
    long n = nbase + nn;
    pw[i] = (n < NTOK) ? P[((long)b * HEADS + h) * NTOK + n] : 0.f;
  }
  __syncthreads();
  int c = tid * 2;
  float wa[HEADS][2];
#pragma unroll
  for (int h = 0; h < HEADS; ++h) { wa[h][0] = 0.f; wa[h][1] = 0.f; }
  int lim = NTOK - nbase; if (lim > 64) lim = 64;
  for (int nn = 0; nn < lim; ++nn) {
    unsigned v = *(const unsigned*)(XT + ((long)b * NTOK + nbase + nn) * HID + c);
    float f0 = bf2f((unsigned short)(v & 0xFFFF));
    float f1 = bf2f((unsigned short)(v >> 16));
#pragma unroll
    for (int h = 0; h < HEADS; ++h) {
      float p = pw[h * 64 + nn];
      wa[h][0] = fmaf(p, f0, wa[h][0]);
      wa[h][1] = fmaf(p, f1, wa[h][1]);
    }
  }
#pragma unroll
  for (int h = 0; h < HEADS; ++h) {
    atomicAdd(&wsum[((long)b * HEADS + h) * HID + c], wa[h][0]);
    atomicAdd(&wsum[((long)b * HEADS + h) * HID + c + 1], wa[h][1]);
  }
}

// ---------------- Opart[b,c] = sum_j wsum[b,h(c),j] * Wv[j,c]  (split-K) ----------------
__global__ void k_o1(const float* __restrict__ wsum, const float* __restrict__ Wv,
                     float* __restrict__ Opart) {
  __shared__ float part[2][128];
  int cblk = blockIdx.x, kc = blockIdx.y, b = blockIdx.z;
  int tid = threadIdx.x;
  int cl = tid & 127, seg = tid >> 7;
  int c = cblk * 128 + cl;
  int h = c >> 6;
  const float* wp = wsum + ((long)b * HEADS + h) * HID;
  int j0 = kc * 64 + seg * 32;
  float a = 0.f;
#pragma unroll 8
  for (int j = j0; j < j0 + 32; ++j) a = fmaf(wp[j], Wv[(long)j * HID + c], a);
  part[seg][cl] = a;
  __syncthreads();
  if (seg == 0) atomicAdd(&Opart[b * HID + c], part[0][cl] + part[1][cl]);
}

// ---------------- t2[b,c] = sum_j so[j]*Wo[j,c], so = qvec+bv+Opart (split-K) ----------------
__global__ void k_o2a(const float* __restrict__ qvec, const float* __restrict__ bv,
                      const float* __restrict__ Opart, const float* __restrict__ Wo,
                      float* __restrict__ t2) {
  __shared__ float part[2][128];
  int cblk = blockIdx.x, kc = blockIdx.y, b = blockIdx.z;
  int tid = threadIdx.x;
  int cl = tid & 127, seg = tid >> 7;
  int c = cblk * 128 + cl;
  int j0 = kc * 64 + seg * 32;
  float a = 0.f;
#pragma unroll 8
  for (int j = j0; j < j0 + 32; ++j) {
    float so = qvec[b * HID + j] + bv[j] + Opart[b * HID + j];
    a = fmaf(so, Wo[(long)j * HID + c], a);
  }
  part[seg][cl] = a;
  __syncthreads();
  if (seg == 0) atomicAdd(&t2[b * HID + c], part[0][cl] + part[1][cl]);
}

// ---------------- o2 = so + relu(t2+bo);  out = o2@Wc + bc ----------------
__global__ void k_o2b(const float* __restrict__ qvec, const float* __restrict__ bv,
                      const float* __restrict__ Opart, const float* __restrict__ bo,
                      const float* __restrict__ t2, const float* __restrict__ Wc,
                      const float* __restrict__ bc, float* __restrict__ out) {
  __shared__ float r0[256], r1[256];
  int b = blockIdx.x, tid = threadIdx.x;
  float s0 = 0.f, s1 = 0.f;
  for (int c = tid; c < HID; c += 256) {
    float so = qvec[b * HID + c] + bv[c] + Opart[b * HID + c];
    float o2 = so + fmaxf(t2[b * HID + c] + bo[c], 0.f);
    s0 = fmaf(o2, Wc[c * 2], s0);
    s1 = fmaf(o2, Wc[c * 2 + 1], s1);
  }
  r0[tid] = s0; r1[tid] = s1;
  __syncthreads();
  for (int s = 128; s; s >>= 1) {
    if (tid < s) { r0[tid] += r0[tid + s]; r1[tid] += r1[tid + s]; }
    __syncthreads();
  }
  if (tid == 0) {
    out[b * NCLS + 0] = r0[0] + bc[0];
    out[b * NCLS + 1] = r1[0] + bc[1];
  }
}

extern "C" void kernel_launch(void* const* d_in, const int* in_sizes, int n_in,
                              void* d_out, int out_size, void* d_ws, size_t ws_size,
                              hipStream_t stream) {
  const float* inputs = (const float*)d_in[0];
  const float* W_feat = (const float*)d_in[1];
  const float* b_feat = (const float*)d_in[2];
  const float* w_enc  = (const float*)d_in[3];
  const float* cls    = (const float*)d_in[5];
  const float* conv_w = (const float*)d_in[6];
  const float* conv_b = (const float*)d_in[7];
  const float* Wq = (const float*)d_in[8];
  const float* bq = (const float*)d_in[9];
  const float* Wk = (const float*)d_in[10];
  const float* bk = (const float*)d_in[11];
  const float* Wv = (const float*)d_in[12];
  const float* bv = (const float*)d_in[13];
  const float* Wo = (const float*)d_in[14];
  const float* bo = (const float*)d_in[15];
  const float* Wc = (const float*)d_in[16];
  const float* bc = (const float*)d_in[17];
  float* out = (float*)d_out;

  char* ws = (char*)d_ws;
  size_t off = 0;
  auto alloc = [&](size_t bytes) -> void* {
    void* p = ws + off;
    off = (off + bytes + 255) & ~(size_t)255;
    return p;
  };
  unsigned short* abf = (unsigned short*)alloc((size_t)MROWS * IND * 2);
  unsigned short* wt  = (unsigned short*)alloc((size_t)HID * IND * 2);
  unsigned short* X   = (unsigned short*)alloc((size_t)MROWS * HID * 2);
  unsigned short* XT  = (unsigned short*)alloc((size_t)BB * NTOK * HID * 2);
  float* u      = (float*)alloc(IND * 4);
  float* slog   = (float*)alloc((size_t)MROWS * 4);
  float* Q      = (float*)alloc(BB * HID * 4);
  float* qvec   = (float*)alloc(BB * HID * 4);
  float* tmat   = (float*)alloc(BB * HEADS * HID * 4);
  float* bkq    = (float*)alloc(BB * HEADS * 4);
  float* logits = (float*)alloc((size_t)BB * HEADS * NTOK * 4);
  float* wsum   = (float*)alloc(BB * HEADS * HID * 4);
  float* Opart  = (float*)alloc(BB * HID * 4);
  float* t2buf  = (float*)alloc(BB * HID * 4);

  k_u<<<IND / 4, 256, 0, stream>>>(W_feat, w_enc, u);
  k_wt<<<dim3(IND / 64, HID / 64), 256, 0, stream>>>(W_feat, wt);
  k_cvt<<<MROWS / 4, 256, 0, stream>>>(inputs, u, abf, slog);
  k_gemm<<<dim3(MROWS / 128, HID / 256), 512, 0, stream>>>(abf, wt, b_feat, X);
  k_topq<<<BB, 1024, 0, stream>>>(slog, X, Q);
  k_conv<<<dim3((NPIX + 7) / 8, BB), 256, 0, stream>>>(X, Q, conv_w, conv_b, XT);
  k_qkprep<<<dim3(HEADS, BB), 256, 0, stream>>>(Q, Wq, bq, Wk, bk, cls, qvec, tmat, bkq, XT);
  k_logits<<<dim3(132, BB), 256, 0, stream>>>(XT, tmat, bkq, logits);
  k_soft<<<BB * HEADS, 256, 0, stream>>>(logits, wsum, Opart, t2buf);
  k_wsum<<<dim3((NTOK + 63) / 64, BB), 256, 0, stream>>>(XT, logits, wsum);
  k_o1<<<dim3(HID / 128, 8, BB), 256, 0, stream>>>(wsum, Wv, Opart);
  k_o2a<<<dim3(HID / 128, 8, BB), 256, 0, stream>>>(qvec, bv, Opart, Wo, t2buf);
  k_o2b<<<BB, 256, 0, stream>>>(qvec, bv, Opart, bo, t2buf, Wc, bc, out);
}

// Round 4
// 472.311 us; speedup vs baseline: 1.6739x; 1.1442x over previous
//
#include <hip/hip_runtime.h>
#include <math.h>

#define BB 4
#define NN 8192
#define IND 1024
#define HID 512
#define HEADS 8
#define KSEL 16
#define NCLS 2
#define HH 91
#define NPIX 8281   // 91*91
#define NTOK 8282   // +cls
#define MROWS 32768 // B*N

typedef short short8 __attribute__((ext_vector_type(8)));
typedef float floatx4 __attribute__((ext_vector_type(4)));

__device__ __forceinline__ unsigned short f2bf(float f) {
  union { float f; unsigned u; } v; v.f = f;
  unsigned r = (v.u + 0x7FFFu + ((v.u >> 16) & 1u)) >> 16;
  return (unsigned short)r;
}
__device__ __forceinline__ float bf2f(unsigned short h) {
  union { unsigned u; float f; } v; v.u = ((unsigned)h) << 16;
  return v.f;
}

__device__ __forceinline__ void gld16(const unsigned short* g, void* l) {
  typedef __attribute__((address_space(1))) const void GV;
  typedef __attribute__((address_space(3))) void LV;
  __builtin_amdgcn_global_load_lds((GV*)g, (LV*)l, 16, 0, 0);
}

// ---------------- u = W_feat @ w_enc (fp32, exact scores path) ----------------
__global__ void k_u(const float* __restrict__ W, const float* __restrict__ we,
                    float* __restrict__ u) {
  int wave = threadIdx.x >> 6, lane = threadIdx.x & 63;
  int k = blockIdx.x * 4 + wave;
  const float* wr = W + (long)k * HID + lane * 8;
  const float* wer = we + lane * 8;
  float a = 0.f;
#pragma unroll
  for (int i = 0; i < 8; ++i) a = fmaf(wr[i], wer[i], a);
  for (int off = 32; off; off >>= 1) a += __shfl_down(a, off);
  if (lane == 0) u[k] = a;
}

// ---------------- W_feat -> bf16 transposed [n][k] ----------------
__global__ void k_wt(const float* __restrict__ W, unsigned short* __restrict__ Wt) {
  __shared__ unsigned short s[64][68];
  int kt = blockIdx.x * 64, nt = blockIdx.y * 64;
  int tid = threadIdx.x;
#pragma unroll
  for (int i = 0; i < 16; ++i) {
    int idx = tid + i * 256;
    int kk2 = idx >> 6, nn2 = idx & 63;
    s[nn2][kk2] = f2bf(W[(long)(kt + kk2) * HID + nt + nn2]);
  }
  __syncthreads();
#pragma unroll
  for (int i = 0; i < 16; ++i) {
    int idx = tid + i * 256;
    int nn2 = idx >> 6, kk2 = idx & 63;
    Wt[(long)(nt + nn2) * IND + kt + kk2] = s[nn2][kk2];
  }
}

// ------------- inputs fp32 -> bf16 copy + exact fp32 score logits -------------
__global__ void k_cvt(const float* __restrict__ in, const float* __restrict__ u,
                      unsigned short* __restrict__ abf, float* __restrict__ slog) {
  __shared__ float su[IND];
  int tid = threadIdx.x;
  for (int i = tid; i < IND; i += 256) su[i] = u[i];
  __syncthreads();
  int wave = tid >> 6, lane = tid & 63;
  long row = (long)blockIdx.x * 4 + wave;
  const float* ip = in + row * IND;
  unsigned short* op = abf + row * IND;
  float acc = 0.f;
#pragma unroll
  for (int p = 0; p < 4; ++p) {
    int k = p * 256 + lane * 4;
    float4 v = *(const float4*)(ip + k);
    ushort4 o;
    o.x = f2bf(v.x); o.y = f2bf(v.y); o.z = f2bf(v.z); o.w = f2bf(v.w);
    *(ushort4*)(op + k) = o;
    acc += v.x * su[k] + v.y * su[k + 1] + v.z * su[k + 2] + v.w * su[k + 3];
  }
  for (int off = 32; off; off >>= 1) acc += __shfl_down(acc, off);
  if (lane == 0) slog[row] = acc;
}

// ------- GEMM1: x = inputs @ W_feat + b_feat (bf16 MFMA, 128x256 tile, 8 waves) -------
__global__ __launch_bounds__(512) void k_gemm(const unsigned short* __restrict__ A,
                                              const unsigned short* __restrict__ Bt,
                                              const float* __restrict__ bias,
                                              unsigned short* __restrict__ X) {
  __shared__ unsigned short sA[128 * 32];
  __shared__ unsigned short sB[256 * 32];
  int tid = threadIdx.x;
  int wave = tid >> 6, lane = tid & 63;
  long m0 = (long)blockIdx.x * 128;
  int n0 = blockIdx.y * 256;
  int wm = (wave >> 2) * 64, wn = (wave & 3) * 64;
  int lm = lane & 15, lk = (lane >> 4) * 8;
  floatx4 acc[4][4];
#pragma unroll
  for (int i = 0; i < 4; ++i)
#pragma unroll
    for (int j = 0; j < 4; ++j) acc[i][j] = (floatx4){0.f, 0.f, 0.f, 0.f};

  const unsigned short* gA = A + (m0 + (tid >> 2)) * IND + (tid & 3) * 8;
  const unsigned short* gB = Bt + (long)(n0 + (tid >> 2)) * IND + (tid & 3) * 8;
  char* sAc = (char*)sA + wave * 1024;
  char* sBc = (char*)sB + wave * 1024;

  for (int k0 = 0; k0 < IND; k0 += 32) {
    gld16(gA + k0, sAc);
    gld16(gB + k0, sBc);
    gld16(gB + k0 + 128 * IND, sBc + 8192);
    __syncthreads();
    short8 af[4], bfr[4];
#pragma unroll
    for (int i = 0; i < 4; ++i)
      af[i] = *(const short8*)(sA + (wm + i * 16 + lm) * 32 + lk);
#pragma unroll
    for (int j = 0; j < 4; ++j)
      bfr[j] = *(const short8*)(sB + (wn + j * 16 + lm) * 32 + lk);
#pragma unroll
    for (int i = 0; i < 4; ++i)
#pragma unroll
      for (int j = 0; j < 4; ++j)
        acc[i][j] = __builtin_amdgcn_mfma_f32_16x16x32_bf16(af[i], bfr[j], acc[i][j], 0, 0, 0);
    __syncthreads();
  }
#pragma unroll
  for (int j = 0; j < 4; ++j) {
    int gcol = n0 + wn + j * 16 + lm;
    float bv_ = bias[gcol];
#pragma unroll
    for (int i = 0; i < 4; ++i) {
      long grow = m0 + wm + i * 16 + (lane >> 4) * 4;
#pragma unroll
      for (int r = 0; r < 4; ++r)
        X[(grow + r) * HID + gcol] = f2bf(acc[i][j][r] + bv_);
    }
  }
}

// ------- top-K (exact fp32 scores), 1024 thr, wave-shuffle reduce; Q = mean -------
__global__ __launch_bounds__(1024) void k_topq(const float* __restrict__ slog,
                                               const unsigned short* __restrict__ X,
                                               float* __restrict__ Q) {
  __shared__ float sc[NN];
  __shared__ float wvs[16];
  __shared__ int wis[16];
  __shared__ int wi[KSEL];
  int b = blockIdx.x, tid = threadIdx.x;
  int lane = tid & 63, wid = tid >> 6;
  for (int i = tid; i < NN; i += 1024) sc[i] = slog[b * NN + i];
  __syncthreads();
  for (int it = 0; it < KSEL; ++it) {
    float bv = -3.4e38f; int bi = 0x7FFFFFFF;
#pragma unroll
    for (int r = 0; r < 8; ++r) {
      int i = tid + r * 1024;
      float v = sc[i];
      if (v > bv || (v == bv && i < bi)) { bv = v; bi = i; }
    }
    for (int off = 32; off; off >>= 1) {
      float v2 = __shfl_down(bv, off);
      int i2 = __shfl_down(bi, off);
      if (v2 > bv || (v2 == bv && i2 < bi)) { bv = v2; bi = i2; }
    }
    if (lane == 0) { wvs[wid] = bv; wis[wid] = bi; }
    __syncthreads();
    if (tid == 0) {
      float best = wvs[0]; int besti = wis[0];
#pragma unroll
      for (int w = 1; w < 16; ++w)
        if (wvs[w] > best || (wvs[w] == best && wis[w] < besti)) { best = wvs[w]; besti = wis[w]; }
      wi[it] = besti;
      sc[besti] = -3.4e38f;
    }
    __syncthreads();
  }
  if (tid < HID) {
    float s = 0.f;
#pragma unroll
    for (int t2 = 0; t2 < KSEL; ++t2)
      s += bf2f(X[((long)b * NN + wi[t2]) * HID + tid]);
    Q[b * HID + tid] = s * (1.f / KSEL);
  }
}

// ------- x2 = relu(x - Q); depthwise 3x3 conv (SAME) + conv_b + residual -> x̃ rows 1.. -------
__global__ void k_conv(const unsigned short* __restrict__ X, const float* __restrict__ Q,
                       const float* __restrict__ cw, const float* __restrict__ cb,
                       unsigned short* __restrict__ XT) {
  int tid = threadIdx.x;
  int b = blockIdx.y;
  int c = tid * 2;
  float w0[9], w1[9];
#pragma unroll
  for (int t = 0; t < 9; ++t) { w0[t] = cw[c * 9 + t]; w1[t] = cw[(c + 1) * 9 + t]; }
  float q0 = Q[b * HID + c], q1 = Q[b * HID + c + 1];
  float cb0 = cb[c], cb1 = cb[c + 1];
  int nbase = blockIdx.x * 8;
  const unsigned short* xb = X + (long)b * NN * HID;
#pragma unroll
  for (int ii = 0; ii < 8; ++ii) {
    int n = nbase + ii;
    if (n >= NPIX) break;
    int h = n / HH, w = n - h * HH;
    float a0 = 0.f, a1 = 0.f, c0v = 0.f, c1v = 0.f;
#pragma unroll
    for (int dy = 0; dy < 3; ++dy) {
      int hh2 = h + dy - 1;
      if (hh2 < 0 || hh2 >= HH) continue;
#pragma unroll
      for (int dx = 0; dx < 3; ++dx) {
        int ww2 = w + dx - 1;
        if (ww2 < 0 || ww2 >= HH) continue;
        int n2 = hh2 * HH + ww2;
        int r = n2 < NN ? n2 : n2 - NN;
        unsigned v = *(const unsigned*)(xb + (long)r * HID + c);
        float f0 = bf2f((unsigned short)(v & 0xFFFF));
        float f1 = bf2f((unsigned short)(v >> 16));
        f0 = fmaxf(f0 - q0, 0.f);
        f1 = fmaxf(f1 - q1, 0.f);
        int t = dy * 3 + dx;
        a0 = fmaf(w0[t], f0, a0);
        a1 = fmaf(w1[t], f1, a1);
        if (t == 4) { c0v = f0; c1v = f1; }
      }
    }
    unsigned out = (unsigned)f2bf(a0 + cb0 + c0v) | ((unsigned)f2bf(a1 + cb1 + c1v) << 16);
    *(unsigned*)(XT + ((long)b * NTOK + 1 + n) * HID + c) = out;
  }
}

// ---------------- qvec = Q@Wq + bq (64 cols per block); cls row of x̃ ----------------
__global__ void k_qv(const float* __restrict__ Q, const float* __restrict__ Wq,
                     const float* __restrict__ bq, const float* __restrict__ cls,
                     float* __restrict__ qvec, unsigned short* __restrict__ XT) {
  __shared__ float sq[HID];
  __shared__ float part[4][64];
  int b = blockIdx.y, cblk = blockIdx.x, tid = threadIdx.x;
  for (int i = tid; i < HID; i += 256) sq[i] = Q[b * HID + i];
  __syncthreads();
  int cl = tid & 63, seg = tid >> 6;
  int c = cblk * 64 + cl;
  float a = 0.f;
#pragma unroll 8
  for (int j = seg * 128; j < seg * 128 + 128; ++j)
    a = fmaf(sq[j], Wq[(long)j * HID + c], a);
  part[seg][cl] = a;
  __syncthreads();
  if (seg == 0)
    qvec[b * HID + c] = part[0][cl] + part[1][cl] + part[2][cl] + part[3][cl] + bq[c];
  if (cblk == 0)
    for (int i = tid; i < HID; i += 256)
      XT[(long)b * NTOK * HID + i] = f2bf(cls[i]);
}

// ------- t[b,h,j] = Σ_d Wk[j,h*64+d]·qvec[b,h*64+d]  — one wave per j-row -------
// lane l covers elements l*8..l*8+7 of Wk row j (head = l>>3); 3-step xor-reduce
// within 8-lane groups yields all 8 head dots per row simultaneously.
__global__ void k_tprep(const float* __restrict__ qvec, const float* __restrict__ Wk,
                        const float* __restrict__ bk, float* __restrict__ tmat,
                        float* __restrict__ bkq) {
  __shared__ float qv[HID];
  int b = blockIdx.y, tid = threadIdx.x;
  for (int i = tid; i < HID; i += 256) qv[i] = qvec[b * HID + i];
  __syncthreads();
  int wave = tid >> 6, lane = tid & 63;
  float q8[8];
#pragma unroll
  for (int i = 0; i < 8; ++i) q8[i] = qv[lane * 8 + i];
#pragma unroll
  for (int jj = 0; jj < 4; ++jj) {
    int j = blockIdx.x * 16 + wave * 4 + jj;
    const float* wr = Wk + (long)j * HID + lane * 8;
    float4 a0 = *(const float4*)wr;
    float4 a1 = *(const float4*)(wr + 4);
    float s = a0.x * q8[0] + a0.y * q8[1] + a0.z * q8[2] + a0.w * q8[3] +
              a1.x * q8[4] + a1.y * q8[5] + a1.z * q8[6] + a1.w * q8[7];
#pragma unroll
    for (int off = 1; off < 8; off <<= 1) s += __shfl_xor(s, off);
    if ((lane & 7) == 0)
      tmat[((long)b * HEADS + (lane >> 3)) * HID + j] = s;
  }
  if (blockIdx.x == 0 && wave == 0) {
    float s = 0.f;
#pragma unroll
    for (int i = 0; i < 8; ++i) s += bk[lane * 8 + i] * q8[i];
#pragma unroll
    for (int off = 1; off < 8; off <<= 1) s += __shfl_xor(s, off);
    if ((lane & 7) == 0) bkq[b * HEADS + (lane >> 3)] = s;
  }
}

// ---------------- logits[b,h,n] = (x̃[n]·t[h] + bkq[h]) / sqrt(512) ----------------
__global__ void k_logits(const unsigned short* __restrict__ XT, const float* __restrict__ tmat,
                         const float* __restrict__ bkq, float* __restrict__ logits) {
  __shared__ float st[HEADS * HID];
  __shared__ float sb[HEADS];
  int b = blockIdx.y, tid = threadIdx.x;
  for (int i = tid; i < HEADS * HID; i += 256) st[i] = tmat[(long)b * HEADS * HID + i];
  if (tid < HEADS) sb[tid] = bkq[b * HEADS + tid];
  __syncthreads();
  int wave = tid >> 6, lane = tid & 63;
  float tr[HEADS][8];
#pragma unroll
  for (int h = 0; h < HEADS; ++h)
#pragma unroll
    for (int i = 0; i < 8; ++i) tr[h][i] = st[h * HID + lane * 8 + i];
  float sbr[HEADS];
#pragma unroll
  for (int h = 0; h < HEADS; ++h) sbr[h] = sb[h];

  for (long row = blockIdx.x * 4 + wave; row < NTOK; row += 4L * gridDim.x) {
    const unsigned short* xr = XT + ((long)b * NTOK + row) * HID + lane * 8;
    ushort4 v0 = *(const ushort4*)xr;
    ushort4 v1 = *(const ushort4*)(xr + 4);
    float xf[8] = {bf2f(v0.x), bf2f(v0.y), bf2f(v0.z), bf2f(v0.w),
                   bf2f(v1.x), bf2f(v1.y), bf2f(v1.z), bf2f(v1.w)};
    float acc[HEADS];
#pragma unroll
    for (int h = 0; h < HEADS; ++h) {
      float a = 0.f;
#pragma unroll
      for (int i = 0; i < 8; ++i) a = fmaf(xf[i], tr[h][i], a);
      acc[h] = a;
    }
#pragma unroll
    for (int h = 0; h < HEADS; ++h)
      for (int off = 32; off; off >>= 1) acc[h] += __shfl_down(acc[h], off);
    if (lane == 0) {
#pragma unroll
      for (int h = 0; h < HEADS; ++h)
        logits[((long)b * HEADS + h) * NTOK + row] = (acc[h] + sbr[h]) * 0.044194173824159216f;
    }
  }
}

// ------- softmax, one block per (b,h); also zero-inits wsum/Opart/t2 slices -------
__global__ void k_soft(float* __restrict__ logits, float* __restrict__ wsum,
                       float* __restrict__ Opart, float* __restrict__ t2) {
  __shared__ float sl[NTOK];
  __shared__ float red[256];
  int bh = blockIdx.x, tid = threadIdx.x;
  int b = bh >> 3, h = bh & 7;
  for (int i = tid; i < HID; i += 256) wsum[(long)bh * HID + i] = 0.f;
  if (tid < 64) {
    Opart[b * HID + h * 64 + tid] = 0.f;
    t2[b * HID + h * 64 + tid] = 0.f;
  }
  float* lp = logits + (long)bh * NTOK;
  for (int i = tid; i < NTOK; i += 256) sl[i] = lp[i];
  __syncthreads();
  float m = -3.4e38f;
  for (int i = tid; i < NTOK; i += 256) m = fmaxf(m, sl[i]);
  red[tid] = m; __syncthreads();
  for (int s = 128; s; s >>= 1) { if (tid < s) red[tid] = fmaxf(red[tid], red[tid + s]); __syncthreads(); }
  m = red[0]; __syncthreads();
  float sm = 0.f;
  for (int i = tid; i < NTOK; i += 256) {
    float e = __expf(sl[i] - m);
    sl[i] = e;
    sm += e;
  }
  red[tid] = sm; __syncthreads();
  for (int s = 128; s; s >>= 1) { if (tid < s) red[tid] += red[tid + s]; __syncthreads(); }
  float inv = 1.f / red[0];
  __syncthreads();
  for (int i = tid; i < NTOK; i += 256) lp[i] = sl[i] * inv;
}

// ---------------- wsum[b,h,:] = sum_n P[h,n] * x̃[n,:] ----------------
__global__ void k_wsum(const unsigned short* __restrict__ XT, const float* __restrict__ P,
                       float* __restrict__ wsum) {
  __shared__ float pw[HEADS * 64];
  int b = blockIdx.y, tid = threadIdx.x;
  int nbase = blockIdx.x * 64;
  for (int i = tid; i < HEADS * 64; i += 256) {
    int h = i >> 6, nn = i & 63;
    long n = nbase + nn;
    pw[i] = (n < NTOK) ? P[((long)b * HEADS + h) * NTOK + n] : 0.f;
  }
  __syncthreads();
  int c = tid * 2;
  float wa[HEADS][2];
#pragma unroll
  for (int h = 0; h < HEADS; ++h) { wa[h][0] = 0.f; wa[h][1] = 0.f; }
  int lim = NTOK - nbase; if (lim > 64) lim = 64;
  for (int nn = 0; nn < lim; ++nn) {
    unsigned v = *(const unsigned*)(XT + ((long)b * NTOK + nbase + nn) * HID + c);
    float f0 = bf2f((unsigned short)(v & 0xFFFF));
    float f1 = bf2f((unsigned short)(v >> 16));
#pragma unroll
    for (int h = 0; h < HEADS; ++h) {
      float p = pw[h * 64 + nn];
      wa[h][0] = fmaf(p, f0, wa[h][0]);
      wa[h][1] = fmaf(p, f1, wa[h][1]);
    }
  }
#pragma unroll
  for (int h = 0; h < HEADS; ++h) {
    atomicAdd(&wsum[((long)b * HEADS + h) * HID + c], wa[h][0]);
    atomicAdd(&wsum[((long)b * HEADS + h) * HID + c + 1], wa[h][1]);
  }
}

// ---------------- Opart[b,c] = sum_j wsum[b,h(c),j] * Wv[j,c]  (split-K) ----------------
__global__ void k_o1(const float* __restrict__ wsum, const float* __restrict__ Wv,
                     float* __restrict__ Opart) {
  __shared__ float part[2][128];
  int cblk = blockIdx.x, kc = blockIdx.y, b = blockIdx.z;
  int tid = threadIdx.x;
  int cl = tid & 127, seg = tid >> 7;
  int c = cblk * 128 + cl;
  int h = c >> 6;
  const float* wp = wsum + ((long)b * HEADS + h) * HID;
  int j0 = kc * 64 + seg * 32;
  float a = 0.f;
#pragma unroll 8
  for (int j = j0; j < j0 + 32; ++j) a = fmaf(wp[j], Wv[(long)j * HID + c], a);
  part[seg][cl] = a;
  __syncthreads();
  if (seg == 0) atomicAdd(&Opart[b * HID + c], part[0][cl] + part[1][cl]);
}

// ---------------- t2[b,c] = sum_j so[j]*Wo[j,c], so = qvec+bv+Opart (split-K) ----------------
__global__ void k_o2a(const float* __restrict__ qvec, const float* __restrict__ bv,
                      const float* __restrict__ Opart, const float* __restrict__ Wo,
                      float* __restrict__ t2) {
  __shared__ float part[2][128];
  int cblk = blockIdx.x, kc = blockIdx.y, b = blockIdx.z;
  int tid = threadIdx.x;
  int cl = tid & 127, seg = tid >> 7;
  int c = cblk * 128 + cl;
  int j0 = kc * 64 + seg * 32;
  float a = 0.f;
#pragma unroll 8
  for (int j = j0; j < j0 + 32; ++j) {
    float so = qvec[b * HID + j] + bv[j] + Opart[b * HID + j];
    a = fmaf(so, Wo[(long)j * HID + c], a);
  }
  part[seg][cl] = a;
  __syncthreads();
  if (seg == 0) atomicAdd(&t2[b * HID + c], part[0][cl] + part[1][cl]);
}

// ---------------- o2 = so + relu(t2+bo);  out = o2@Wc + bc ----------------
__global__ void k_o2b(const float* __restrict__ qvec, const float* __restrict__ bv,
                      const float* __restrict__ Opart, const float* __restrict__ bo,
                      const float* __restrict__ t2, const float* __restrict__ Wc,
                      const float* __restrict__ bc, float* __restrict__ out) {
  __shared__ float r0[256], r1[256];
  int b = blockIdx.x, tid = threadIdx.x;
  float s0 = 0.f, s1 = 0.f;
  for (int c = tid; c < HID; c += 256) {
    float so = qvec[b * HID + c] + bv[c] + Opart[b * HID + c];
    float o2 = so + fmaxf(t2[b * HID + c] + bo[c], 0.f);
    s0 = fmaf(o2, Wc[c * 2], s0);
    s1 = fmaf(o2, Wc[c * 2 + 1], s1);
  }
  r0[tid] = s0; r1[tid] = s1;
  __syncthreads();
  for (int s = 128; s; s >>= 1) {
    if (tid < s) { r0[tid] += r0[tid + s]; r1[tid] += r1[tid + s]; }
    __syncthreads();
  }
  if (tid == 0) {
    out[b * NCLS + 0] = r0[0] + bc[0];
    out[b * NCLS + 1] = r1[0] + bc[1];
  }
}

extern "C" void kernel_launch(void* const* d_in, const int* in_sizes, int n_in,
                              void* d_out, int out_size, void* d_ws, size_t ws_size,
                              hipStream_t stream) {
  const float* inputs = (const float*)d_in[0];
  const float* W_feat = (const float*)d_in[1];
  const float* b_feat = (const float*)d_in[2];
  const float* w_enc  = (const float*)d_in[3];
  const float* cls    = (const float*)d_in[5];
  const float* conv_w = (const float*)d_in[6];
  const float* conv_b = (const float*)d_in[7];
  const float* Wq = (const float*)d_in[8];
  const float* bq = (const float*)d_in[9];
  const float* Wk = (const float*)d_in[10];
  const float* bk = (const float*)d_in[11];
  const float* Wv = (const float*)d_in[12];
  const float* bv = (const float*)d_in[13];
  const float* Wo = (const float*)d_in[14];
  const float* bo = (const float*)d_in[15];
  const float* Wc = (const float*)d_in[16];
  const float* bc = (const float*)d_in[17];
  float* out = (float*)d_out;

  char* ws = (char*)d_ws;
  size_t off = 0;
  auto alloc = [&](size_t bytes) -> void* {
    void* p = ws + off;
    off = (off + bytes + 255) & ~(size_t)255;
    return p;
  };
  unsigned short* abf = (unsigned short*)alloc((size_t)MROWS * IND * 2);
  unsigned short* wt  = (unsigned short*)alloc((size_t)HID * IND * 2);
  unsigned short* X   = (unsigned short*)alloc((size_t)MROWS * HID * 2);
  unsigned short* XT  = (unsigned short*)alloc((size_t)BB * NTOK * HID * 2);
  float* u      = (float*)alloc(IND * 4);
  float* slog   = (float*)alloc((size_t)MROWS * 4);
  float* Q      = (float*)alloc(BB * HID * 4);
  float* qvec   = (float*)alloc(BB * HID * 4);
  float* tmat   = (float*)alloc(BB * HEADS * HID * 4);
  float* bkq    = (float*)alloc(BB * HEADS * 4);
  float* logits = (float*)alloc((size_t)BB * HEADS * NTOK * 4);
  float* wsum   = (float*)alloc(BB * HEADS * HID * 4);
  float* Opart  = (float*)alloc(BB * HID * 4);
  float* t2buf  = (float*)alloc(BB * HID * 4);

  k_u<<<IND / 4, 256, 0, stream>>>(W_feat, w_enc, u);
  k_wt<<<dim3(IND / 64, HID / 64), 256, 0, stream>>>(W_feat, wt);
  k_cvt<<<MROWS / 4, 256, 0, stream>>>(inputs, u, abf, slog);
  k_gemm<<<dim3(MROWS / 128, HID / 256), 512, 0, stream>>>(abf, wt, b_feat, X);
  k_topq<<<BB, 1024, 0, stream>>>(slog, X, Q);
  k_conv<<<dim3((NPIX + 7) / 8, BB), 256, 0, stream>>>(X, Q, conv_w, conv_b, XT);
  k_qv<<<dim3(HID / 64, BB), 256, 0, stream>>>(Q, Wq, bq, cls, qvec, XT);
  k_tprep<<<dim3(HID / 16, BB), 256, 0, stream>>>(qvec, Wk, bk, tmat, bkq);
  k_logits<<<dim3(132, BB), 256, 0, stream>>>(XT, tmat, bkq, logits);
  k_soft<<<BB * HEADS, 256, 0, stream>>>(logits, wsum, Opart, t2buf);
  k_wsum<<<dim3((NTOK + 63) / 64, BB), 256, 0, stream>>>(XT, logits, wsum);
  k_o1<<<dim3(HID / 128, 8, BB), 256, 0, stream>>>(wsum, Wv, Opart);
  k_o2a<<<dim3(HID / 128, 8, BB), 256, 0, stream>>>(qvec, bv, Opart, Wo, t2buf);
  k_o2b<<<BB, 256, 0, stream>>>(qvec, bv, Opart, bo, t2buf, Wc, bc, out);
}

// Round 5
// 465.891 us; speedup vs baseline: 1.6970x; 1.0138x over previous
//
#include <hip/hip_runtime.h>
#include <math.h>

#define BB 4
#define NN 8192
#define IND 1024
#define HID 512
#define HEADS 8
#define KSEL 16
#define NCLS 2
#define HH 91
#define NPIX 8281   // 91*91
#define NTOK 8282   // +cls
#define MROWS 32768 // B*N

typedef short short8 __attribute__((ext_vector_type(8)));
typedef float floatx4 __attribute__((ext_vector_type(4)));

__device__ __forceinline__ unsigned short f2bf(float f) {
  union { float f; unsigned u; } v; v.f = f;
  unsigned r = (v.u + 0x7FFFu + ((v.u >> 16) & 1u)) >> 16;
  return (unsigned short)r;
}
__device__ __forceinline__ float bf2f(unsigned short h) {
  union { unsigned u; float f; } v; v.u = ((unsigned)h) << 16;
  return v.f;
}

__device__ __forceinline__ void gld16(const unsigned short* g, void* l) {
  typedef __attribute__((address_space(1))) const void GV;
  typedef __attribute__((address_space(3))) void LV;
  __builtin_amdgcn_global_load_lds((GV*)g, (LV*)l, 16, 0, 0);
}

// ---------------- u = W_feat @ w_enc (fp32, exact scores path) ----------------
__global__ void k_u(const float* __restrict__ W, const float* __restrict__ we,
                    float* __restrict__ u) {
  int wave = threadIdx.x >> 6, lane = threadIdx.x & 63;
  int k = blockIdx.x * 4 + wave;
  const float* wr = W + (long)k * HID + lane * 8;
  const float* wer = we + lane * 8;
  float a = 0.f;
#pragma unroll
  for (int i = 0; i < 8; ++i) a = fmaf(wr[i], wer[i], a);
  for (int off = 32; off; off >>= 1) a += __shfl_down(a, off);
  if (lane == 0) u[k] = a;
}

// ---------------- W_feat -> bf16 transposed [n][k] ----------------
__global__ void k_wt(const float* __restrict__ W, unsigned short* __restrict__ Wt) {
  __shared__ unsigned short s[64][68];
  int kt = blockIdx.x * 64, nt = blockIdx.y * 64;
  int tid = threadIdx.x;
#pragma unroll
  for (int i = 0; i < 16; ++i) {
    int idx = tid + i * 256;
    int kk2 = idx >> 6, nn2 = idx & 63;
    s[nn2][kk2] = f2bf(W[(long)(kt + kk2) * HID + nt + nn2]);
  }
  __syncthreads();
#pragma unroll
  for (int i = 0; i < 16; ++i) {
    int idx = tid + i * 256;
    int nn2 = idx >> 6, kk2 = idx & 63;
    Wt[(long)(nt + nn2) * IND + kt + kk2] = s[nn2][kk2];
  }
}

// ------------- inputs fp32 -> bf16 copy + exact fp32 score logits -------------
__global__ void k_cvt(const float* __restrict__ in, const float* __restrict__ u,
                      unsigned short* __restrict__ abf, float* __restrict__ slog) {
  __shared__ float su[IND];
  int tid = threadIdx.x;
  for (int i = tid; i < IND; i += 256) su[i] = u[i];
  __syncthreads();
  int wave = tid >> 6, lane = tid & 63;
  long row = (long)blockIdx.x * 4 + wave;
  const float* ip = in + row * IND;
  unsigned short* op = abf + row * IND;
  float acc = 0.f;
#pragma unroll
  for (int p = 0; p < 4; ++p) {
    int k = p * 256 + lane * 4;
    float4 v = *(const float4*)(ip + k);
    ushort4 o;
    o.x = f2bf(v.x); o.y = f2bf(v.y); o.z = f2bf(v.z); o.w = f2bf(v.w);
    *(ushort4*)(op + k) = o;
    acc += v.x * su[k] + v.y * su[k + 1] + v.z * su[k + 2] + v.w * su[k + 3];
  }
  for (int off = 32; off; off >>= 1) acc += __shfl_down(acc, off);
  if (lane == 0) slog[row] = acc;
}

// ------- GEMM1: 128x128 tile, 256 thr, BK=64 via two [128][32] sub-buffers -------
// (m103: 128^2 is the tile sweet spot; BK=64 halves barrier count vs BK=32)
__global__ __launch_bounds__(256) void k_gemm(const unsigned short* __restrict__ A,
                                              const unsigned short* __restrict__ Bt,
                                              const float* __restrict__ bias,
                                              unsigned short* __restrict__ X) {
  __shared__ unsigned short sA[2][128 * 32];
  __shared__ unsigned short sB[2][128 * 32];
  int tid = threadIdx.x;
  int wave = tid >> 6, lane = tid & 63;
  long m0 = (long)blockIdx.x * 128;
  int n0 = blockIdx.y * 128;
  int wm = (wave >> 1) * 64, wn = (wave & 1) * 64;
  int lm = lane & 15, lk = (lane >> 4) * 8;
  floatx4 acc[4][4];
#pragma unroll
  for (int i = 0; i < 4; ++i)
#pragma unroll
    for (int j = 0; j < 4; ++j) acc[i][j] = (floatx4){0.f, 0.f, 0.f, 0.f};

  const unsigned short* gA = A + (m0 + (tid >> 2)) * IND + (tid & 3) * 8;
  const unsigned short* gB = Bt + (long)(n0 + (tid >> 2)) * IND + (tid & 3) * 8;
  char* a0 = (char*)sA[0] + wave * 1024;
  char* a1 = (char*)sA[1] + wave * 1024;
  char* b0 = (char*)sB[0] + wave * 1024;
  char* b1 = (char*)sB[1] + wave * 1024;

  for (int k0 = 0; k0 < IND; k0 += 64) {
    gld16(gA + k0, a0);
    gld16(gA + k0 + 64 * IND, a0 + 4096);
    gld16(gA + k0 + 32, a1);
    gld16(gA + k0 + 32 + 64 * IND, a1 + 4096);
    gld16(gB + k0, b0);
    gld16(gB + k0 + 64 * IND, b0 + 4096);
    gld16(gB + k0 + 32, b1);
    gld16(gB + k0 + 32 + 64 * IND, b1 + 4096);
    __syncthreads();
#pragma unroll
    for (int ks = 0; ks < 2; ++ks) {
      short8 af[4], bfr[4];
#pragma unroll
      for (int i = 0; i < 4; ++i)
        af[i] = *(const short8*)(sA[ks] + (wm + i * 16 + lm) * 32 + lk);
#pragma unroll
      for (int j = 0; j < 4; ++j)
        bfr[j] = *(const short8*)(sB[ks] + (wn + j * 16 + lm) * 32 + lk);
#pragma unroll
      for (int i = 0; i < 4; ++i)
#pragma unroll
        for (int j = 0; j < 4; ++j)
          acc[i][j] = __builtin_amdgcn_mfma_f32_16x16x32_bf16(af[i], bfr[j], acc[i][j], 0, 0, 0);
    }
    __syncthreads();
  }
#pragma unroll
  for (int j = 0; j < 4; ++j) {
    int gcol = n0 + wn + j * 16 + lm;
    float bv_ = bias[gcol];
#pragma unroll
    for (int i = 0; i < 4; ++i) {
      long grow = m0 + wm + i * 16 + (lane >> 4) * 4;
#pragma unroll
      for (int r = 0; r < 4; ++r)
        X[(grow + r) * HID + gcol] = f2bf(acc[i][j][r] + bv_);
    }
  }
}

// ------- top-K phase A: per-512-slice local top-16 (64 blocks of parallelism) -------
__global__ void k_topa(const float* __restrict__ slog, float* __restrict__ cval,
                       int* __restrict__ cidx) {
  __shared__ float sc[512];
  __shared__ float wv[4];
  __shared__ int wiL[4];
  int b = blockIdx.y, blk = blockIdx.x, tid = threadIdx.x;
  int base = b * NN + blk * 512;
  sc[tid] = slog[base + tid];
  sc[tid + 256] = slog[base + tid + 256];
  __syncthreads();
  int lane = tid & 63, wid = tid >> 6;
  for (int it = 0; it < KSEL; ++it) {
    float v0 = sc[tid], v1 = sc[tid + 256];
    float bv; int bi;
    if (v1 > v0) { bv = v1; bi = tid + 256; } else { bv = v0; bi = tid; }
    for (int off = 32; off; off >>= 1) {
      float v2 = __shfl_down(bv, off);
      int i2 = __shfl_down(bi, off);
      if (v2 > bv || (v2 == bv && i2 < bi)) { bv = v2; bi = i2; }
    }
    if (lane == 0) { wv[wid] = bv; wiL[wid] = bi; }
    __syncthreads();
    if (tid == 0) {
      float best = wv[0]; int besti = wiL[0];
#pragma unroll
      for (int w = 1; w < 4; ++w)
        if (wv[w] > best || (wv[w] == best && wiL[w] < besti)) { best = wv[w]; besti = wiL[w]; }
      cval[(b * 16 + blk) * 16 + it] = best;
      cidx[(b * 16 + blk) * 16 + it] = blk * 512 + besti;
      sc[besti] = -3.4e38f;
    }
    __syncthreads();
  }
}

// ------- top-K phase B: merge 256 candidates -> global top-16; Q = mean -------
__global__ void k_topb(const float* __restrict__ cval, const int* __restrict__ cidx,
                       const unsigned short* __restrict__ X, float* __restrict__ Q) {
  __shared__ float cv[256];
  __shared__ int ci[256];
  __shared__ float wv[4];
  __shared__ int wiL[4];
  __shared__ int wsl[4];
  __shared__ int wi[KSEL];
  int b = blockIdx.x, tid = threadIdx.x;
  cv[tid] = cval[b * 256 + tid];
  ci[tid] = cidx[b * 256 + tid];
  __syncthreads();
  int lane = tid & 63, wid = tid >> 6;
  for (int it = 0; it < KSEL; ++it) {
    float bv = cv[tid]; int bi = ci[tid]; int sl = tid;
    for (int off = 32; off; off >>= 1) {
      float v2 = __shfl_down(bv, off);
      int i2 = __shfl_down(bi, off);
      int s2 = __shfl_down(sl, off);
      if (v2 > bv || (v2 == bv && i2 < bi)) { bv = v2; bi = i2; sl = s2; }
    }
    if (lane == 0) { wv[wid] = bv; wiL[wid] = bi; wsl[wid] = sl; }
    __syncthreads();
    if (tid == 0) {
      float best = wv[0]; int besti = wiL[0]; int bests = wsl[0];
#pragma unroll
      for (int w = 1; w < 4; ++w)
        if (wv[w] > best || (wv[w] == best && wiL[w] < besti)) {
          best = wv[w]; besti = wiL[w]; bests = wsl[w];
        }
      wi[it] = besti;
      cv[bests] = -3.4e38f;
    }
    __syncthreads();
  }
  for (int c = tid; c < HID; c += 256) {
    float s = 0.f;
#pragma unroll
    for (int t2 = 0; t2 < KSEL; ++t2)
      s += bf2f(X[((long)b * NN + wi[t2]) * HID + c]);
    Q[b * HID + c] = s * (1.f / KSEL);
  }
}

// ------- x2 = relu(x - Q); depthwise 3x3 conv (SAME) + conv_b + residual -> x̃ rows 1.. -------
__global__ void k_conv(const unsigned short* __restrict__ X, const float* __restrict__ Q,
                       const float* __restrict__ cw, const float* __restrict__ cb,
                       unsigned short* __restrict__ XT) {
  int tid = threadIdx.x;
  int b = blockIdx.y;
  int c = tid * 2;
  float w0[9], w1[9];
#pragma unroll
  for (int t = 0; t < 9; ++t) { w0[t] = cw[c * 9 + t]; w1[t] = cw[(c + 1) * 9 + t]; }
  float q0 = Q[b * HID + c], q1 = Q[b * HID + c + 1];
  float cb0 = cb[c], cb1 = cb[c + 1];
  int nbase = blockIdx.x * 8;
  const unsigned short* xb = X + (long)b * NN * HID;
#pragma unroll
  for (int ii = 0; ii < 8; ++ii) {
    int n = nbase + ii;
    if (n >= NPIX) break;
    int h = n / HH, w = n - h * HH;
    float a0 = 0.f, a1 = 0.f, c0v = 0.f, c1v = 0.f;
#pragma unroll
    for (int dy = 0; dy < 3; ++dy) {
      int hh2 = h + dy - 1;
      if (hh2 < 0 || hh2 >= HH) continue;
#pragma unroll
      for (int dx = 0; dx < 3; ++dx) {
        int ww2 = w + dx - 1;
        if (ww2 < 0 || ww2 >= HH) continue;
        int n2 = hh2 * HH + ww2;
        int r = n2 < NN ? n2 : n2 - NN;
        unsigned v = *(const unsigned*)(xb + (long)r * HID + c);
        float f0 = bf2f((unsigned short)(v & 0xFFFF));
        float f1 = bf2f((unsigned short)(v >> 16));
        f0 = fmaxf(f0 - q0, 0.f);
        f1 = fmaxf(f1 - q1, 0.f);
        int t = dy * 3 + dx;
        a0 = fmaf(w0[t], f0, a0);
        a1 = fmaf(w1[t], f1, a1);
        if (t == 4) { c0v = f0; c1v = f1; }
      }
    }
    unsigned out = (unsigned)f2bf(a0 + cb0 + c0v) | ((unsigned)f2bf(a1 + cb1 + c1v) << 16);
    *(unsigned*)(XT + ((long)b * NTOK + 1 + n) * HID + c) = out;
  }
}

// ---------------- qvec = Q@Wq + bq (64 cols per block); cls row of x̃ ----------------
__global__ void k_qv(const float* __restrict__ Q, const float* __restrict__ Wq,
                     const float* __restrict__ bq, const float* __restrict__ cls,
                     float* __restrict__ qvec, unsigned short* __restrict__ XT) {
  __shared__ float sq[HID];
  __shared__ float part[4][64];
  int b = blockIdx.y, cblk = blockIdx.x, tid = threadIdx.x;
  for (int i = tid; i < HID; i += 256) sq[i] = Q[b * HID + i];
  __syncthreads();
  int cl = tid & 63, seg = tid >> 6;
  int c = cblk * 64 + cl;
  float a = 0.f;
#pragma unroll 8
  for (int j = seg * 128; j < seg * 128 + 128; ++j)
    a = fmaf(sq[j], Wq[(long)j * HID + c], a);
  part[seg][cl] = a;
  __syncthreads();
  if (seg == 0)
    qvec[b * HID + c] = part[0][cl] + part[1][cl] + part[2][cl] + part[3][cl] + bq[c];
  if (cblk == 0)
    for (int i = tid; i < HID; i += 256)
      XT[(long)b * NTOK * HID + i] = f2bf(cls[i]);
}

// ------- t[b,h,j] = Σ_d Wk[j,h*64+d]·qvec[b,h*64+d]  — one wave per j-row -------
__global__ void k_tprep(const float* __restrict__ qvec, const float* __restrict__ Wk,
                        const float* __restrict__ bk, float* __restrict__ tmat,
                        float* __restrict__ bkq) {
  __shared__ float qv[HID];
  int b = blockIdx.y, tid = threadIdx.x;
  for (int i = tid; i < HID; i += 256) qv[i] = qvec[b * HID + i];
  __syncthreads();
  int wave = tid >> 6, lane = tid & 63;
  float q8[8];
#pragma unroll
  for (int i = 0; i < 8; ++i) q8[i] = qv[lane * 8 + i];
#pragma unroll
  for (int jj = 0; jj < 4; ++jj) {
    int j = blockIdx.x * 16 + wave * 4 + jj;
    const float* wr = Wk + (long)j * HID + lane * 8;
    float4 a0 = *(const float4*)wr;
    float4 a1 = *(const float4*)(wr + 4);
    float s = a0.x * q8[0] + a0.y * q8[1] + a0.z * q8[2] + a0.w * q8[3] +
              a1.x * q8[4] + a1.y * q8[5] + a1.z * q8[6] + a1.w * q8[7];
#pragma unroll
    for (int off = 1; off < 8; off <<= 1) s += __shfl_xor(s, off);
    if ((lane & 7) == 0)
      tmat[((long)b * HEADS + (lane >> 3)) * HID + j] = s;
  }
  if (blockIdx.x == 0 && wave == 0) {
    float s = 0.f;
#pragma unroll
    for (int i = 0; i < 8; ++i) s += bk[lane * 8 + i] * q8[i];
#pragma unroll
    for (int off = 1; off < 8; off <<= 1) s += __shfl_xor(s, off);
    if ((lane & 7) == 0) bkq[b * HEADS + (lane >> 3)] = s;
  }
}

// ---------------- logits[b,h,n] = (x̃[n]·t[h] + bkq[h]) / sqrt(512) ----------------
__global__ void k_logits(const unsigned short* __restrict__ XT, const float* __restrict__ tmat,
                         const float* __restrict__ bkq, float* __restrict__ logits) {
  __shared__ float st[HEADS * HID];
  __shared__ float sb[HEADS];
  int b = blockIdx.y, tid = threadIdx.x;
  for (int i = tid; i < HEADS * HID; i += 256) st[i] = tmat[(long)b * HEADS * HID + i];
  if (tid < HEADS) sb[tid] = bkq[b * HEADS + tid];
  __syncthreads();
  int wave = tid >> 6, lane = tid & 63;
  float tr[HEADS][8];
#pragma unroll
  for (int h = 0; h < HEADS; ++h)
#pragma unroll
    for (int i = 0; i < 8; ++i) tr[h][i] = st[h * HID + lane * 8 + i];
  float sbr[HEADS];
#pragma unroll
  for (int h = 0; h < HEADS; ++h) sbr[h] = sb[h];

  for (long row = blockIdx.x * 4 + wave; row < NTOK; row += 4L * gridDim.x) {
    const unsigned short* xr = XT + ((long)b * NTOK + row) * HID + lane * 8;
    ushort4 v0 = *(const ushort4*)xr;
    ushort4 v1 = *(const ushort4*)(xr + 4);
    float xf[8] = {bf2f(v0.x), bf2f(v0.y), bf2f(v0.z), bf2f(v0.w),
                   bf2f(v1.x), bf2f(v1.y), bf2f(v1.z), bf2f(v1.w)};
    float acc[HEADS];
#pragma unroll
    for (int h = 0; h < HEADS; ++h) {
      float a = 0.f;
#pragma unroll
      for (int i = 0; i < 8; ++i) a = fmaf(xf[i], tr[h][i], a);
      acc[h] = a;
    }
#pragma unroll
    for (int h = 0; h < HEADS; ++h)
      for (int off = 32; off; off >>= 1) acc[h] += __shfl_down(acc[h], off);
    if (lane == 0) {
#pragma unroll
      for (int h = 0; h < HEADS; ++h)
        logits[((long)b * HEADS + h) * NTOK + row] = (acc[h] + sbr[h]) * 0.044194173824159216f;
    }
  }
}

// ------- softmax, one block per (b,h); also zero-inits wsum/Opart/t2 slices -------
__global__ void k_soft(float* __restrict__ logits, float* __restrict__ wsum,
                       float* __restrict__ Opart, float* __restrict__ t2) {
  __shared__ float sl[NTOK];
  __shared__ float red[256];
  int bh = blockIdx.x, tid = threadIdx.x;
  int b = bh >> 3, h = bh & 7;
  for (int i = tid; i < HID; i += 256) wsum[(long)bh * HID + i] = 0.f;
  if (tid < 64) {
    Opart[b * HID + h * 64 + tid] = 0.f;
    t2[b * HID + h * 64 + tid] = 0.f;
  }
  float* lp = logits + (long)bh * NTOK;
  for (int i = tid; i < NTOK; i += 256) sl[i] = lp[i];
  __syncthreads();
  float m = -3.4e38f;
  for (int i = tid; i < NTOK; i += 256) m = fmaxf(m, sl[i]);
  red[tid] = m; __syncthreads();
  for (int s = 128; s; s >>= 1) { if (tid < s) red[tid] = fmaxf(red[tid], red[tid + s]); __syncthreads(); }
  m = red[0]; __syncthreads();
  float sm = 0.f;
  for (int i = tid; i < NTOK; i += 256) {
    float e = __expf(sl[i] - m);
    sl[i] = e;
    sm += e;
  }
  red[tid] = sm; __syncthreads();
  for (int s = 128; s; s >>= 1) { if (tid < s) red[tid] += red[tid + s]; __syncthreads(); }
  float inv = 1.f / red[0];
  __syncthreads();
  for (int i = tid; i < NTOK; i += 256) lp[i] = sl[i] * inv;
}

// ---------------- wsum[b,h,:] = sum_n P[h,n] * x̃[n,:] ----------------
__global__ void k_wsum(const unsigned short* __restrict__ XT, const float* __restrict__ P,
                       float* __restrict__ wsum) {
  __shared__ float pw[HEADS * 64];
  int b = blockIdx.y, tid = threadIdx.x;
  int nbase = blockIdx.x * 64;
  for (int i = tid; i < HEADS * 64; i += 256) {
    int h = i >> 6, nn = i & 63;
    long n = nbase + nn;
    pw[i] = (n < NTOK) ? P[((long)b * HEADS + h) * NTOK + n] : 0.f;
  }
  __syncthreads();
  int c = tid * 2;
  float wa[HEADS][2];
#pragma unroll
  for (int h = 0; h < HEADS; ++h) { wa[h][0] = 0.f; wa[h][1] = 0.f; }
  int lim = NTOK - nbase; if (lim > 64) lim = 64;
  for (int nn = 0; nn < lim; ++nn) {
    unsigned v = *(const unsigned*)(XT + ((long)b * NTOK + nbase + nn) * HID + c);
    float f0 = bf2f((unsigned short)(v & 0xFFFF));
    float f1 = bf2f((unsigned short)(v >> 16));
#pragma unroll
    for (int h = 0; h < HEADS; ++h) {
      float p = pw[h * 64 + nn];
      wa[h][0] = fmaf(p, f0, wa[h][0]);
      wa[h][1] = fmaf(p, f1, wa[h][1]);
    }
  }
#pragma unroll
  for (int h = 0; h < HEADS; ++h) {
    atomicAdd(&wsum[((long)b * HEADS + h) * HID + c], wa[h][0]);
    atomicAdd(&wsum[((long)b * HEADS + h) * HID + c + 1], wa[h][1]);
  }
}

// ---------------- Opart[b,c] = sum_j wsum[b,h(c),j] * Wv[j,c]  (split-K) ----------------
__global__ void k_o1(const float* __restrict__ wsum, const float* __restrict__ Wv,
                     float* __restrict__ Opart) {
  __shared__ float part[2][128];
  int cblk = blockIdx.x, kc = blockIdx.y, b = blockIdx.z;
  int tid = threadIdx.x;
  int cl = tid & 127, seg = tid >> 7;
  int c = cblk * 128 + cl;
  int h = c >> 6;
  const float* wp = wsum + ((long)b * HEADS + h) * HID;
  int j0 = kc * 64 + seg * 32;
  float a = 0.f;
#pragma unroll 8
  for (int j = j0; j < j0 + 32; ++j) a = fmaf(wp[j], Wv[(long)j * HID + c], a);
  part[seg][cl] = a;
  __syncthreads();
  if (seg == 0) atomicAdd(&Opart[b * HID + c], part[0][cl] + part[1][cl]);
}

// ---------------- t2[b,c] = sum_j so[j]*Wo[j,c], so = qvec+bv+Opart (split-K) ----------------
__global__ void k_o2a(const float* __restrict__ qvec, const float* __restrict__ bv,
                      const float* __restrict__ Opart, const float* __restrict__ Wo,
                      float* __restrict__ t2) {
  __shared__ float part[2][128];
  int cblk = blockIdx.x, kc = blockIdx.y, b = blockIdx.z;
  int tid = threadIdx.x;
  int cl = tid & 127, seg = tid >> 7;
  int c = cblk * 128 + cl;
  int j0 = kc * 64 + seg * 32;
  float a = 0.f;
#pragma unroll 8
  for (int j = j0; j < j0 + 32; ++j) {
    float so = qvec[b * HID + j] + bv[j] + Opart[b * HID + j];
    a = fmaf(so, Wo[(long)j * HID + c], a);
  }
  part[seg][cl] = a;
  __syncthreads();
  if (seg == 0) atomicAdd(&t2[b * HID + c], part[0][cl] + part[1][cl]);
}

// ---------------- o2 = so + relu(t2+bo);  out = o2@Wc + bc ----------------
__global__ void k_o2b(const float* __restrict__ qvec, const float* __restrict__ bv,
                      const float* __restrict__ Opart, const float* __restrict__ bo,
                      const float* __restrict__ t2, const float* __restrict__ Wc,
                      const float* __restrict__ bc, float* __restrict__ out) {
  __shared__ float r0[256], r1[256];
  int b = blockIdx.x, tid = threadIdx.x;
  float s0 = 0.f, s1 = 0.f;
  for (int c = tid; c < HID; c += 256) {
    float so = qvec[b * HID + c] + bv[c] + Opart[b * HID + c];
    float o2 = so + fmaxf(t2[b * HID + c] + bo[c], 0.f);
    s0 = fmaf(o2, Wc[c * 2], s0);
    s1 = fmaf(o2, Wc[c * 2 + 1], s1);
  }
  r0[tid] = s0; r1[tid] = s1;
  __syncthreads();
  for (int s = 128; s; s >>= 1) {
    if (tid < s) { r0[tid] += r0[tid + s]; r1[tid] += r1[tid + s]; }
    __syncthreads();
  }
  if (tid == 0) {
    out[b * NCLS + 0] = r0[0] + bc[0];
    out[b * NCLS + 1] = r1[0] + bc[1];
  }
}

extern "C" void kernel_launch(void* const* d_in, const int* in_sizes, int n_in,
                              void* d_out, int out_size, void* d_ws, size_t ws_size,
                              hipStream_t stream) {
  const float* inputs = (const float*)d_in[0];
  const float* W_feat = (const float*)d_in[1];
  const float* b_feat = (const float*)d_in[2];
  const float* w_enc  = (const float*)d_in[3];
  const float* cls    = (const float*)d_in[5];
  const float* conv_w = (const float*)d_in[6];
  const float* conv_b = (const float*)d_in[7];
  const float* Wq = (const float*)d_in[8];
  const float* bq = (const float*)d_in[9];
  const float* Wk = (const float*)d_in[10];
  const float* bk = (const float*)d_in[11];
  const float* Wv = (const float*)d_in[12];
  const float* bv = (const float*)d_in[13];
  const float* Wo = (const float*)d_in[14];
  const float* bo = (const float*)d_in[15];
  const float* Wc = (const float*)d_in[16];
  const float* bc = (const float*)d_in[17];
  float* out = (float*)d_out;

  char* ws = (char*)d_ws;
  size_t off = 0;
  auto alloc = [&](size_t bytes) -> void* {
    void* p = ws + off;
    off = (off + bytes + 255) & ~(size_t)255;
    return p;
  };
  unsigned short* abf = (unsigned short*)alloc((size_t)MROWS * IND * 2);
  unsigned short* wt  = (unsigned short*)alloc((size_t)HID * IND * 2);
  unsigned short* X   = (unsigned short*)alloc((size_t)MROWS * HID * 2);
  unsigned short* XT  = (unsigned short*)alloc((size_t)BB * NTOK * HID * 2);
  float* u      = (float*)alloc(IND * 4);
  float* slog   = (float*)alloc((size_t)MROWS * 4);
  float* cvalb  = (float*)alloc(BB * 256 * 4);
  int*   cidxb  = (int*)alloc(BB * 256 * 4);
  float* Q      = (float*)alloc(BB * HID * 4);
  float* qvec   = (float*)alloc(BB * HID * 4);
  float* tmat   = (float*)alloc(BB * HEADS * HID * 4);
  float* bkq    = (float*)alloc(BB * HEADS * 4);
  float* logits = (float*)alloc((size_t)BB * HEADS * NTOK * 4);
  float* wsum   = (float*)alloc(BB * HEADS * HID * 4);
  float* Opart  = (float*)alloc(BB * HID * 4);
  float* t2buf  = (float*)alloc(BB * HID * 4);

  k_u<<<IND / 4, 256, 0, stream>>>(W_feat, w_enc, u);
  k_wt<<<dim3(IND / 64, HID / 64), 256, 0, stream>>>(W_feat, wt);
  k_cvt<<<MROWS / 4, 256, 0, stream>>>(inputs, u, abf, slog);
  k_gemm<<<dim3(MROWS / 128, HID / 128), 256, 0, stream>>>(abf, wt, b_feat, X);
  k_topa<<<dim3(16, BB), 256, 0, stream>>>(slog, cvalb, cidxb);
  k_topb<<<BB, 256, 0, stream>>>(cvalb, cidxb, X, Q);
  k_conv<<<dim3((NPIX + 7) / 8, BB), 256, 0, stream>>>(X, Q, conv_w, conv_b, XT);
  k_qv<<<dim3(HID / 64, BB), 256, 0, stream>>>(Q, Wq, bq, cls, qvec, XT);
  k_tprep<<<dim3(HID / 16, BB), 256, 0, stream>>>(qvec, Wk, bk, tmat, bkq);
  k_logits<<<dim3(132, BB), 256, 0, stream>>>(XT, tmat, bkq, logits);
  k_soft<<<BB * HEADS, 256, 0, stream>>>(logits, wsum, Opart, t2buf);
  k_wsum<<<dim3((NTOK + 63) / 64, BB), 256, 0, stream>>>(XT, logits, wsum);
  k_o1<<<dim3(HID / 128, 8, BB), 256, 0, stream>>>(wsum, Wv, Opart);
  k_o2a<<<dim3(HID / 128, 8, BB), 256, 0, stream>>>(qvec, bv, Opart, Wo, t2buf);
  k_o2b<<<BB, 256, 0, stream>>>(qvec, bv, Opart, bo, t2buf, Wc, bc, out);
}